// Round 18
// baseline (147.012 us; speedup 1.0000x reference)
//
#include <hip/hip_runtime.h>
#include <hip/hip_bf16.h>

typedef __bf16 bf16x8 __attribute__((ext_vector_type(8)));
typedef float f32x4 __attribute__((ext_vector_type(4)));
using bf16 = __hip_bfloat16;

#define SEQ 2048
#define DM 1024
#define NH 16
#define DH 64
#define NBH 32
#define MR 4096  // B*S

// wait own async loads (vmcnt<=N) then workgroup barrier, as ONE asm block.
#define WAITBAR(N) asm volatile("s_waitcnt vmcnt(" #N ")\n\ts_barrier" ::: "memory")

static __device__ __forceinline__ void async_cp16(const void* gsrc, void* ldsdst) {
  __builtin_amdgcn_global_load_lds((__attribute__((address_space(1))) void*)gsrc,
                                   (__attribute__((address_space(3))) void*)ldsdst, 16, 0, 0);
}

static __device__ __forceinline__ unsigned short f2bfu(float f) {
  bf16 h = __float2bfloat16(f);
  unsigned short u; __builtin_memcpy(&u, &h, 2); return u;
}
static __device__ __forceinline__ unsigned int pack_bf2(float lo, float hi) {
  return (unsigned int)f2bfu(lo) | ((unsigned int)f2bfu(hi) << 16);
}

// ---------------- cast hidden_states to bf16 ----------------
__global__ __launch_bounds__(256) void cast_x(const float* __restrict__ X, bf16* __restrict__ Xb) {
  long g = ((long)blockIdx.x * 256 + threadIdx.x) * 8;
  float4 a = *(const float4*)(X + g);
  float4 b = *(const float4*)(X + g + 4);
  unsigned short u[8];
  u[0]=f2bfu(a.x); u[1]=f2bfu(a.y); u[2]=f2bfu(a.z); u[3]=f2bfu(a.w);
  u[4]=f2bfu(b.x); u[5]=f2bfu(b.y); u[6]=f2bfu(b.z); u[7]=f2bfu(b.w);
  uint4 o; __builtin_memcpy(&o, u, 16);
  *(uint4*)(Xb + g) = o;
}

// ---------------- transpose+cast weights: Wt[n][k] = W[k][n] ----------------
struct WPtrs { const float* w[6]; };

__global__ __launch_bounds__(256) void transpose_cast_w(WPtrs wp, bf16* __restrict__ WtAll) {
  const int z = blockIdx.z;
  const float* W = wp.w[z];
  bf16* Wt = WtAll + (long)z * DM * DM;
  __shared__ float Ts[32][33];
  int n0 = blockIdx.x * 32, k0 = blockIdx.y * 32;
  int tx = threadIdx.x, ty = threadIdx.y;
#pragma unroll
  for (int it = 0; it < 4; ++it)
    Ts[ty + 8*it][tx] = W[(long)(k0 + ty + 8*it) * DM + n0 + tx];
  __syncthreads();
#pragma unroll
  for (int it = 0; it < 4; ++it)
    Wt[(long)(n0 + ty + 8*it) * DM + k0 + tx] = __float2bfloat16(Ts[tx][ty + 8*it]);
}

// ---------------- projection GEMM: heterogeneous grid, zero tail ----------------
// K-order rotated by block parity (karot) to desynchronize co-resident blocks:
// their barrier/drain windows then overlap the other block's compute (m114).
struct ProjArgs {
  const float* bias[5];
  bf16* out[5];
};

__global__ __launch_bounds__(256, 2) void gemm_proj(const bf16* __restrict__ A,
                                                    const bf16* __restrict__ WtAll, ProjArgs p) {
  __shared__ alignas(16) bf16 SM[36864];   // 72KB: As 3x[128][32] | Bs 3x[256][32]
  bf16* As = SM;
  bf16* Bs = SM + 12288;
  const int tid = threadIdx.x;
  const int bid = blockIdx.x;              // 1024 = 512 fat + 512 thin
  const int karot = (bid & 1) * 16;        // K-phase rotation (order-independent sum)
  const int wave = tid >> 6, lane = tid & 63, l15 = lane & 15, l4 = lane >> 4;
  const int wm = wave >> 1, wn = wave & 1;
  const int slot8 = (l4 ^ ((l15 >> 1) & 3)) * 8;
  const int prow = tid >> 2;
  const int cc = (tid & 3) ^ ((prow >> 1) & 3);
  char* dA = (char*)As + wave * 1024;
  char* dB = (char*)Bs + wave * 1024;

  if (bid < 512) {
    // ================= FAT: 128x256 over z = 0..3 =================
    const int mt = bid & 31, nt = bid >> 5;  // nt 0..15
    const int m0 = mt * 128;
    const int z = nt >> 2;
    const int n0z = (nt & 3) * 256;
    const bf16* Bt = WtAll + (long)z * DM * DM + (long)n0z * DM;

    const bf16* sA0 = A  + (long)(m0 + prow) * DM + cc * 8;
    const bf16* sA1 = sA0 + 64L * DM;
    const bf16* sB0 = Bt + (long)prow * DM + cc * 8;
    const bf16* sB1 = sB0 + 64L * DM;
    const bf16* sB2 = sB0 + 128L * DM;
    const bf16* sB3 = sB0 + 192L * DM;

#define PSTAGE(KT_, BUF_) do {                                  \
    int ko_ = (((KT_) + karot) & 31) * 32;                      \
    async_cp16(sA0 + ko_, dA + (BUF_) * 8192);                  \
    async_cp16(sA1 + ko_, dA + (BUF_) * 8192 + 4096);           \
    async_cp16(sB0 + ko_, dB + (BUF_) * 16384);                 \
    async_cp16(sB1 + ko_, dB + (BUF_) * 16384 + 4096);          \
    async_cp16(sB2 + ko_, dB + (BUF_) * 16384 + 8192);          \
    async_cp16(sB3 + ko_, dB + (BUF_) * 16384 + 12288);         \
  } while (0)

    const int arow = wm * 64 + l15;
    const int brow = wn * 128 + l15;
    f32x4 acc[4][8] = {};

#define PCOMPUTE(BUF_) do {                                                        \
    const bf16* ab_ = As + (BUF_) * 4096;                                          \
    const bf16* bb_ = Bs + (BUF_) * 8192;                                          \
    bf16x8 af_[4], bq_[8];                                                         \
    _Pragma("unroll")                                                              \
    for (int i = 0; i < 4; ++i) af_[i] = *(const bf16x8*)(ab_ + (arow + i * 16) * 32 + slot8); \
    _Pragma("unroll")                                                              \
    for (int j = 0; j < 8; ++j) bq_[j] = *(const bf16x8*)(bb_ + (brow + j * 16) * 32 + slot8); \
    _Pragma("unroll")                                                              \
    for (int i = 0; i < 4; ++i)                                                    \
      _Pragma("unroll")                                                            \
      for (int j = 0; j < 8; ++j)                                                  \
        acc[i][j] = __builtin_amdgcn_mfma_f32_16x16x32_bf16(af_[i], bq_[j], acc[i][j], 0, 0, 0); \
  } while (0)

    PSTAGE(0, 0);
    PSTAGE(1, 1);
    int buf = 0;
#pragma unroll 1
    for (int k = 0; k < 31; ++k) {
      WAITBAR(6);            // own stage(k) landed (stage(k+1)'s 6 ops in flight)
      if (k < 30) {
        int nb = buf + 2; if (nb > 2) nb -= 3;
        PSTAGE(k + 2, nb);
      }
      PCOMPUTE(buf);
      ++buf; if (buf > 2) buf = 0;
    }
    WAITBAR(0);
    PCOMPUTE(buf);
#undef PSTAGE
#undef PCOMPUTE

    // -------- epilogue (fat) --------
    const float* bias = p.bias[z];
    bf16* out = p.out[z];
    float bv[8];
#pragma unroll
    for (int j = 0; j < 8; ++j) bv[j] = bias[n0z + wn * 128 + j * 16 + l15];

    if (z < 2) {
      const float scale = (z == 0) ? 0.125f * 1.44269504f : 1.0f;
#pragma unroll
      for (int i = 0; i < 4; ++i)
#pragma unroll
        for (int j = 0; j < 8; ++j)
#pragma unroll
          for (int r = 0; r < 4; ++r) {
            int m = m0 + wm * 64 + i * 16 + l4 * 4 + r;
            int n = n0z + wn * 128 + j * 16 + l15;
            int b = m >> 11, s = m & 2047, hh = n >> 6, d = n & 63;
            out[((long)((b * NH + hh) * SEQ + s)) * DH + d] =
                __float2bfloat16((acc[i][j][r] + bv[j]) * scale);
          }
    } else {
      // transposed [BH][DH][S] via LDS bounce -> 256B-contiguous stores per thread
      __syncthreads();
      bf16* Os = SM;                           // [256 n][136 stride]
#pragma unroll
      for (int i = 0; i < 4; ++i)
#pragma unroll
        for (int j = 0; j < 8; ++j)
#pragma unroll
          for (int r = 0; r < 4; ++r) {
            int nl = wn * 128 + j * 16 + l15;
            int ml = wm * 64 + i * 16 + l4 * 4 + r;
            Os[nl * 136 + ml] = __float2bfloat16(acc[i][j][r] + bv[j]);
          }
      __syncthreads();
      {
        int nl = tid;
        int ng = n0z + nl;
        int hh = ng >> 6, d = ng & 63;
        int b = m0 >> 11, s0 = m0 & 2047;
        bf16* op = out + ((long)((b * NH + hh) * DH + d)) * SEQ + s0;
#pragma unroll
        for (int u = 0; u < 16; ++u)
          *(bf16x8*)(op + u * 8) = *(const bf16x8*)(Os + nl * 136 + u * 8);
      }
    }
  } else {
    // ================= THIN: 128x64 over v2 (z=4) =================
    const int tb = bid - 512;
    const int mt = tb & 31, nt16 = tb >> 5;   // 0..15
    const int m0 = mt * 128, n0 = nt16 * 64;
    const bf16* Bt = WtAll + 4L * DM * DM + (long)n0 * DM;

    const bf16* sA0 = A + (long)(m0 + prow) * DM + cc * 8;
    const bf16* sA1 = sA0 + 64L * DM;
    const bf16* sB0 = Bt + (long)prow * DM + cc * 8;   // prow 0..63 covers all 64 rows

#define TSTAGE(KT_, BUF_) do {                                  \
    int ko_ = (((KT_) + karot) & 31) * 32;                      \
    async_cp16(sA0 + ko_, dA + (BUF_) * 8192);                  \
    async_cp16(sA1 + ko_, dA + (BUF_) * 8192 + 4096);           \
    async_cp16(sB0 + ko_, dB + (BUF_) * 4096);                  \
  } while (0)

    const int arow = wm * 64 + l15;
    const int brow = wn * 32 + l15;
    f32x4 acc2[4][2] = {};

#define TCOMPUTE(BUF_) do {                                                        \
    const bf16* ab_ = As + (BUF_) * 4096;                                          \
    const bf16* bb_ = Bs + (BUF_) * 2048;                                          \
    bf16x8 af_[4], bq_[2];                                                         \
    _Pragma("unroll")                                                              \
    for (int i = 0; i < 4; ++i) af_[i] = *(const bf16x8*)(ab_ + (arow + i * 16) * 32 + slot8); \
    _Pragma("unroll")                                                              \
    for (int j = 0; j < 2; ++j) bq_[j] = *(const bf16x8*)(bb_ + (brow + j * 16) * 32 + slot8); \
    _Pragma("unroll")                                                              \
    for (int i = 0; i < 4; ++i)                                                    \
      _Pragma("unroll")                                                            \
      for (int j = 0; j < 2; ++j)                                                  \
        acc2[i][j] = __builtin_amdgcn_mfma_f32_16x16x32_bf16(af_[i], bq_[j], acc2[i][j], 0, 0, 0); \
  } while (0)

    TSTAGE(0, 0);
    TSTAGE(1, 1);
    int buf = 0;
#pragma unroll 1
    for (int k = 0; k < 31; ++k) {
      WAITBAR(3);            // own stage(k)'s 3 loads landed (stage(k+1) in flight)
      if (k < 30) {
        int nb = buf + 2; if (nb > 2) nb -= 3;
        TSTAGE(k + 2, nb);
      }
      TCOMPUTE(buf);
      ++buf; if (buf > 2) buf = 0;
    }
    WAITBAR(0);
    TCOMPUTE(buf);
#undef TSTAGE
#undef TCOMPUTE

    // -------- epilogue (thin, transposed [BH][DH][S]) --------
    float bv2[2];
#pragma unroll
    for (int j = 0; j < 2; ++j) bv2[j] = p.bias[4][n0 + wn * 32 + j * 16 + l15];
    __syncthreads();
    bf16* Os = SM;                             // [64][136] = 17KB
#pragma unroll
    for (int i = 0; i < 4; ++i)
#pragma unroll
      for (int j = 0; j < 2; ++j)
#pragma unroll
        for (int r = 0; r < 4; ++r) {
          int nl = wn * 32 + j * 16 + l15;
          int ml = wm * 64 + i * 16 + l4 * 4 + r;
          Os[nl * 136 + ml] = __float2bfloat16(acc2[i][j][r] + bv2[j]);
        }
    __syncthreads();
    {
      int nl = tid & 63, seg = tid >> 6;       // 4 segs x 32 elems
      int ng = n0 + nl;
      int hh = ng >> 6, d = ng & 63;
      int b = m0 >> 11, s0 = m0 & 2047;
      bf16* op = p.out[4] + ((long)((b * NH + hh) * DH + d)) * SEQ + s0 + seg * 32;
#pragma unroll
      for (int u = 0; u < 4; ++u)
        *(bf16x8*)(op + u * 8) = *(const bf16x8*)(Os + nl * 136 + seg * 32 + u * 8);
    }
  }
}

// ---------------- final GEMM: 128x64 tiles, 512 blocks (2/CU), ring-3 ----------------
__global__ __launch_bounds__(256, 3) void gemm_out(const bf16* __restrict__ A, const bf16* __restrict__ Bt,
                                                   const float* __restrict__ bias, float* __restrict__ out) {
  __shared__ alignas(16) bf16 As[3 * 128 * 32];  // 24KB
  __shared__ alignas(16) bf16 Bs[3 * 64 * 32];   // 12KB
  const int tid = threadIdx.x;
  const int bid = blockIdx.x;            // 512 = 16 n x 32 m
  const int karot = (bid & 1) * 16;      // K-phase desync
  const int nt = bid & 15, mt = bid >> 4;
  const int m0 = mt * 128, n0 = nt * 64;
  const int wave = tid >> 6, lane = tid & 63, l15 = lane & 15, l4 = lane >> 4;
  const int wm = wave >> 1, wn = wave & 1;
  const int slot8 = (l4 ^ ((l15 >> 1) & 3)) * 8;
  const int prow = tid >> 2;
  const int cc = (tid & 3) ^ ((prow >> 1) & 3);
  const bf16* sA0 = A + (long)(m0 + prow) * DM + cc * 8;
  const bf16* sA1 = sA0 + 64L * DM;
  const bf16* sB0 = Bt + (long)(n0 + prow) * DM + cc * 8;  // prow 0..63 covers the 64 n-rows
  char* dA = (char*)As + wave * 1024;
  char* dB = (char*)Bs + wave * 1024;

#define OSTAGE(KT_, BUF_) do {                                  \
    int ko_ = (((KT_) + karot) & 31) * 32;                      \
    async_cp16(sA0 + ko_, dA + (BUF_) * 8192);                  \
    async_cp16(sA1 + ko_, dA + (BUF_) * 8192 + 4096);           \
    async_cp16(sB0 + ko_, dB + (BUF_) * 4096);                  \
  } while (0)

  const int arow = wm * 64 + l15;
  const int brow = wn * 32 + l15;
  f32x4 acc2[4][2] = {};

#define OCOMPUTE(BUF_) do {                                                        \
    const bf16* ab_ = As + (BUF_) * 4096;                                          \
    const bf16* bb_ = Bs + (BUF_) * 2048;                                          \
    bf16x8 af_[4], bq_[2];                                                         \
    _Pragma("unroll")                                                              \
    for (int i = 0; i < 4; ++i) af_[i] = *(const bf16x8*)(ab_ + (arow + i * 16) * 32 + slot8); \
    _Pragma("unroll")                                                              \
    for (int j = 0; j < 2; ++j) bq_[j] = *(const bf16x8*)(bb_ + (brow + j * 16) * 32 + slot8); \
    _Pragma("unroll")                                                              \
    for (int i = 0; i < 4; ++i)                                                    \
      _Pragma("unroll")                                                            \
      for (int j = 0; j < 2; ++j)                                                  \
        acc2[i][j] = __builtin_amdgcn_mfma_f32_16x16x32_bf16(af_[i], bq_[j], acc2[i][j], 0, 0, 0); \
  } while (0)

  OSTAGE(0, 0);
  OSTAGE(1, 1);
  int buf = 0;
#pragma unroll 1
  for (int k = 0; k < 31; ++k) {
    WAITBAR(3);
    if (k < 30) {
      int nb = buf + 2; if (nb > 2) nb -= 3;
      OSTAGE(k + 2, nb);
    }
    OCOMPUTE(buf);
    ++buf; if (buf > 2) buf = 0;
  }
  WAITBAR(0);
  OCOMPUTE(buf);
#undef OSTAGE
#undef OCOMPUTE

  float bv[2];
#pragma unroll
  for (int j = 0; j < 2; ++j) bv[j] = bias[n0 + wn * 32 + j * 16 + l15];
#pragma unroll
  for (int i = 0; i < 4; ++i)
#pragma unroll
    for (int j = 0; j < 2; ++j)
#pragma unroll
      for (int r = 0; r < 4; ++r) {
        int m = m0 + wm * 64 + i * 16 + l4 * 4 + r;
        int n = n0 + wn * 32 + j * 16 + l15;
        out[(long)m * DM + n] = acc2[i][j][r] + bv[j];
      }
}

// ---------------- M[b,h] = k2^T v2  (64x64 per head, f32 atomics) ----------------
__global__ __launch_bounds__(256) void m_kernel(
    const bf16* __restrict__ k2t, const bf16* __restrict__ v2t, float* __restrict__ Mbuf)
{
  const int scx = blockIdx.x;  // s chunk 0..7 (256 each)
  const int bh = blockIdx.y;
  const int tid = threadIdx.x, wave = tid >> 6, lane = tid & 63, l15 = lane & 15, l4 = lane >> 4;
  const bf16* kp = k2t + (long)bh * DH * SEQ;
  const bf16* vp = v2t + (long)bh * DH * SEQ;
  __shared__ alignas(16) bf16 K2s[64 * 32];
  __shared__ alignas(16) bf16 V2s[64 * 32];
  f32x4 acc[4] = {};
  const int s0 = scx * 256;
  for (int kk = 0; kk < 256; kk += 32) {
    __syncthreads();
    {
      int c = tid, r = c >> 2, pp = c & 3;
      async_cp16(kp + (long)r * SEQ + s0 + kk + pp * 8, K2s + wave * 64 * 8);
      async_cp16(vp + (long)r * SEQ + s0 + kk + pp * 8, V2s + wave * 64 * 8);
    }
    __syncthreads();
    int arow = 16 * wave + l15;
    bf16x8 a = *(const bf16x8*)(K2s + arow * 32 + l4 * 8);
#pragma unroll
    for (int nb = 0; nb < 4; ++nb) {
      int col = nb * 16 + l15;
      bf16x8 b = *(const bf16x8*)(V2s + col * 32 + l4 * 8);
      acc[nb] = __builtin_amdgcn_mfma_f32_16x16x32_bf16(a, b, acc[nb], 0, 0, 0);
    }
  }
  float* Mp = Mbuf + (long)bh * 4096;
#pragma unroll
  for (int nb = 0; nb < 4; ++nb)
#pragma unroll
    for (int r = 0; r < 4; ++r) {
      int row = 16 * wave + l4 * 4 + r;
      int col = nb * 16 + l15;
      atomicAdd(Mp + row * 64 + col, acc[nb][r]);
    }
}

// -------- cross-lane redistribution: acc layout -> B-frag layout ----------
static __device__ __forceinline__ void redist(const unsigned int (&pk)[4][2], bf16x8 (&pb)[2],
                                              int l4, int l15) {
#pragma unroll
  for (int h = 0; h < 2; ++h) {
    unsigned int w4[4];
#pragma unroll
    for (int w = 0; w < 4; ++w) {
      int src = l15 + 16 * (2 * (l4 & 1) + (w >> 1));
      unsigned int va = (unsigned int)__shfl((int)pk[2 * h][w & 1], src);
      unsigned int vb = (unsigned int)__shfl((int)pk[2 * h + 1][w & 1], src);
      w4[w] = (l4 & 2) ? vb : va;
    }
    __builtin_memcpy(&pb[h], w4, 16);
  }
}

// ---------------- fused flash attention + ctx2: paired q-tiles, KVBLK=128 ----------------
// XCD-aware mapping (T1) + s_setprio around MFMA clusters (T5, m191) +
// exact defer-max (round-9 proven: skip rescale when sf==1).
__global__ __launch_bounds__(256) void attn_fused(
    const bf16* __restrict__ q,    // [BH][S][DH], pre-scaled by log2e/8
    const bf16* __restrict__ k1,   // [BH][S][DH]
    const bf16* __restrict__ v1t,  // [BH][DH][S]
    const float* __restrict__ Mbuf,// [BH][64][64]
    bf16* __restrict__ ctx2)       // [B][S][DM]
{
  const int bid = blockIdx.x;      // 0..511
  const int xcd = bid & 7, ii = bid >> 3;
  const int bh = (xcd << 2) | (ii & 3);    // head group per XCD
  const int qpair = ii >> 2;               // 0..15
  const int bb = bh >> 4, hh = bh & 15;
  const int tid = threadIdx.x, wave = tid >> 6, lane = tid & 63;
  const int l15 = lane & 15, l4 = lane >> 4;
  const bf16* qp = q   + (long)bh * SEQ * DH;
  const bf16* kp = k1  + (long)bh * SEQ * DH;
  const bf16* vp = v1t + (long)bh * DH * SEQ;
  const float* Mp = Mbuf + (long)bh * 4096;

  __shared__ alignas(16) bf16 Ks[2][128 * 64];   // [kv][d], 8 chunks/row, phys = c ^ (kv&7)
  __shared__ alignas(16) bf16 Vs[2][64 * 128];   // [d][kv], 16 chunks/row, phys = c ^ (d&15)

  bf16x8 mf[4][2];
#pragma unroll
  for (int db = 0; db < 4; ++db)
#pragma unroll
    for (int h = 0; h < 2; ++h) {
      bf16x8 t;
#pragma unroll
      for (int j = 0; j < 8; ++j)
        t[j] = (__bf16)Mp[(32 * h + 8 * l4 + j) * 64 + 16 * db + l15];
      mf[db][h] = t;
    }

#define STAGE_KV(JJ, BUF) do {                                                     \
    int kv0_ = 128 * (JJ);                                                         \
    int cK_ = (tid & 7) ^ ((tid >> 3) & 7);                                        \
    int cV_ = (tid & 15) ^ ((tid >> 4) & 15);                                      \
    _Pragma("unroll")                                                              \
    for (int p_ = 0; p_ < 4; ++p_) {                                               \
      int rK_ = (tid >> 3) + 32 * p_;                                              \
      async_cp16(kp + (long)(kv0_ + rK_) * DH + cK_ * 8,                           \
                 (char*)Ks[BUF] + p_ * 4096 + wave * 1024);                        \
      int rV_ = (tid >> 4) + 16 * p_;                                              \
      async_cp16(vp + (long)rV_ * SEQ + kv0_ + cV_ * 8,                            \
                 (char*)Vs[BUF] + p_ * 4096 + wave * 1024);                        \
    }                                                                              \
  } while (0)

#pragma unroll 1
  for (int half = 0; half < 2; ++half) {
    const int tq = (half == 0) ? (31 - qpair) : qpair;   // big tile first
    const int Q0 = 64 * tq;
    const int qg = Q0 + 16 * wave + l15;
    const int jm = tq >> 1;          // last 128-kv tile index

    __syncthreads();                 // prev half's epilogue LDS reads done
    STAGE_KV(0, 0);

    bf16x8 aq[2];
#pragma unroll
    for (int h = 0; h < 2; ++h)
      aq[h] = *(const bf16x8*)(qp + (long)qg * DH + 32 * h + 8 * l4);

    float m_run = -__builtin_inff(), l_run = 0.f;
    f32x4 acc_o[4] = {};

    __syncthreads();                 // stage(0) drained

#pragma unroll 1
    for (int j = 0; j <= jm; ++j) {
      const int cur = j & 1;
      if (j < jm) STAGE_KV(j + 1, cur ^ 1);

      // ---- QK^T (swapped): sc[nb] rows = kv (16nb+..), cols = q ----
      f32x4 sc[8] = {};
      __builtin_amdgcn_s_setprio(1);
#pragma unroll
      for (int nb = 0; nb < 8; ++nb) {
        const bf16* krow = Ks[cur] + (16 * nb + l15) * 64;
#pragma unroll
        for (int h = 0; h < 2; ++h) {
          bf16x8 kf = *(const bf16x8*)(krow + (((4 * h + l4) ^ (l15 & 7)) * 8));
          sc[nb] = __builtin_amdgcn_mfma_f32_16x16x32_bf16(kf, aq[h], sc[nb], 0, 0, 0);
        }
      }
      __builtin_amdgcn_s_setprio(0);

      if (j == jm) {   // diagonal 128-tile: mask kv > q
        const int kv0 = 128 * j;
#pragma unroll
        for (int nb = 0; nb < 8; ++nb)
#pragma unroll
          for (int r = 0; r < 4; ++r)
            if (kv0 + 16 * nb + 4 * l4 + r > qg) sc[nb][r] = -__builtin_inff();
      }

      // ---- softmax (per-lane row, exp2 domain) ----
      float tmax = -__builtin_inff();
#pragma unroll
      for (int nb = 0; nb < 8; ++nb)
#pragma unroll
        for (int r = 0; r < 4; ++r) tmax = fmaxf(tmax, sc[nb][r]);
      tmax = fmaxf(tmax, __shfl_xor(tmax, 16));
      tmax = fmaxf(tmax, __shfl_xor(tmax, 32));

      if (!__all(tmax <= m_run)) {   // exact defer-max: skipped branch has sf == 1
        float mnew = fmaxf(m_run, tmax);
        float sf = __builtin_amdgcn_exp2f(m_run - mnew);
        m_run = mnew;
        l_run *= sf;
#pragma unroll
        for (int db = 0; db < 4; ++db)
#pragma unroll
          for (int r = 0; r < 4; ++r) acc_o[db][r] *= sf;
      }

      float ssum = 0.f;
      unsigned int pkA[4][2], pkB[4][2];
#pragma unroll
      for (int nb = 0; nb < 4; ++nb)
#pragma unroll
        for (int pr = 0; pr < 2; ++pr) {
          float p0 = __builtin_amdgcn_exp2f(sc[nb][2 * pr]     - m_run);
          float p1 = __builtin_amdgcn_exp2f(sc[nb][2 * pr + 1] - m_run);
          ssum += p0 + p1;
          pkA[nb][pr] = pack_bf2(p0, p1);
        }
#pragma unroll
      for (int nb = 0; nb < 4; ++nb)
#pragma unroll
        for (int pr = 0; pr < 2; ++pr) {
          float p0 = __builtin_amdgcn_exp2f(sc[nb + 4][2 * pr]     - m_run);
          float p1 = __builtin_amdgcn_exp2f(sc[nb + 4][2 * pr + 1] - m_run);
          ssum += p0 + p1;
          pkB[nb][pr] = pack_bf2(p0, p1);
        }
      ssum += __shfl_xor(ssum, 16);
      ssum += __shfl_xor(ssum, 32);
      l_run += ssum;

      // ---- P -> B-frag layout (two 64-kv halves), then PV over 4 kv-slices ----
      bf16x8 pbA[2], pbB[2];
      redist(pkA, pbA, l4, l15);
      redist(pkB, pbB, l4, l15);
      __builtin_amdgcn_s_setprio(1);
#pragma unroll
      for (int db = 0; db < 4; ++db) {
        const bf16* vrow = Vs[cur] + (16 * db + l15) * 128;
#pragma unroll
        for (int hs = 0; hs < 2; ++hs) {
          bf16x8 vf = *(const bf16x8*)(vrow + (((4 * hs + l4) ^ l15) * 8));
          acc_o[db] = __builtin_amdgcn_mfma_f32_16x16x32_bf16(vf, pbA[hs], acc_o[db], 0, 0, 0);
        }
#pragma unroll
        for (int hs = 0; hs < 2; ++hs) {
          bf16x8 vf = *(const bf16x8*)(vrow + (((4 * (hs + 2) + l4) ^ l15) * 8));
          acc_o[db] = __builtin_amdgcn_mfma_f32_16x16x32_bf16(vf, pbB[hs], acc_o[db], 0, 0, 0);
        }
      }
      __builtin_amdgcn_s_setprio(0);
      __syncthreads();   // staged tile j+1 drained; buffers swappable
    }

    // ---- epilogue: ctx1 = acc/l ; ctx2_tile = ctx1 @ M  (8 MFMA) ----
    float invl = __builtin_amdgcn_rcpf(l_run);
    unsigned int ck[4][2];
#pragma unroll
    for (int db = 0; db < 4; ++db)
#pragma unroll
      for (int pr = 0; pr < 2; ++pr)
        ck[db][pr] = pack_bf2(acc_o[db][2 * pr] * invl, acc_o[db][2 * pr + 1] * invl);
    bf16x8 cb[2];
    redist(ck, cb, l4, l15);
    f32x4 o2[4] = {};
#pragma unroll
    for (int db = 0; db < 4; ++db)
#pragma unroll
      for (int h = 0; h < 2; ++h)
        o2[db] = __builtin_amdgcn_mfma_f32_16x16x32_bf16(mf[db][h], cb[h], o2[db], 0, 0, 0);

    // o2: row = d' = 16db+4*l4+r, col = q = l15 -> transpose via padded LDS, store coalesced
    bf16* Os = (bf16*)Ks;   // 64 x 72 pad = 9216 elems, fits easily
#pragma unroll
    for (int db = 0; db < 4; ++db)
#pragma unroll
      for (int r = 0; r < 4; ++r)
        Os[(16 * wave + l15) * 72 + 16 * db + 4 * l4 + r] = __float2bfloat16(o2[db][r]);
    __syncthreads();
    {
      int rr = tid >> 2, cc2 = tid & 3;
      long obase = ((long)(bb * SEQ + Q0 + rr)) * DM + hh * DH + cc2 * 16;
      *(bf16x8*)(ctx2 + obase)     = *(const bf16x8*)(Os + rr * 72 + cc2 * 16);
      *(bf16x8*)(ctx2 + obase + 8) = *(const bf16x8*)(Os + rr * 72 + cc2 * 16 + 8);
    }
  }
#undef STAGE_KV
}

// ---------------- launch ----------------
extern "C" void kernel_launch(void* const* d_in, const int* in_sizes, int n_in,
                              void* d_out, int out_size, void* d_ws, size_t ws_size,
                              hipStream_t stream) {
  (void)in_sizes; (void)n_in; (void)out_size; (void)ws_size;
  const float* X = (const float*)d_in[0];
  const float* W[6]    = {(const float*)d_in[1], (const float*)d_in[3], (const float*)d_in[5],
                          (const float*)d_in[7], (const float*)d_in[9], (const float*)d_in[11]};
  const float* bias[6] = {(const float*)d_in[2], (const float*)d_in[4], (const float*)d_in[6],
                          (const float*)d_in[8], (const float*)d_in[10], (const float*)d_in[12]};

  char* ws = (char*)d_ws;
  bf16* Xb  = (bf16*)(ws);                 // 8 MB (reused as ctx2 after proj GEMM done)
  bf16* Wt  = (bf16*)(ws + (8L  << 20));   // 12 MB (6 x 2MB)
  bf16* qB  = (bf16*)(ws + (20L << 20));   // 8 MB  [BH][S][DH]
  bf16* k1B = (bf16*)(ws + (28L << 20));   // 8 MB  [BH][S][DH]
  bf16* k2t = (bf16*)(ws + (36L << 20));   // 8 MB  [BH][DH][S]
  bf16* v1t = (bf16*)(ws + (44L << 20));   // 8 MB  [BH][DH][S]
  bf16* v2t = (bf16*)(ws + (52L << 20));   // 8 MB  [BH][DH][S]
  float* Mb = (float*)(ws + (60L << 20));  // 512 KB
  bf16* c2  = Xb;                          // reuse: ctx2 [4096][1024]

  cast_x<<<2048, 256, 0, stream>>>(X, Xb);

  WPtrs wp; for (int z = 0; z < 6; ++z) wp.w[z] = W[z];
  transpose_cast_w<<<dim3(32, 32, 6), dim3(32, 8), 0, stream>>>(wp, Wt);

  ProjArgs pa;
  for (int z = 0; z < 5; ++z) pa.bias[z] = bias[z];
  pa.out[0] = qB; pa.out[1] = k1B; pa.out[2] = k2t; pa.out[3] = v1t; pa.out[4] = v2t;
  gemm_proj<<<1024, 256, 0, stream>>>(Xb, Wt, pa);

  hipMemsetAsync(Mb, 0, (size_t)NBH * 4096 * 4, stream);
  m_kernel<<<dim3(8, 32), 256, 0, stream>>>(k2t, v2t, Mb);

  attn_fused<<<512, 256, 0, stream>>>(qB, k1B, v1t, Mb, c2);

  gemm_out<<<512, 256, 0, stream>>>(c2, Wt + 5L * DM * DM, bias[5], (float*)d_out);
}

// Round 19
// 146.434 us; speedup vs baseline: 1.0039x; 1.0039x over previous
//
#include <hip/hip_runtime.h>
#include <hip/hip_bf16.h>

typedef __bf16 bf16x8 __attribute__((ext_vector_type(8)));
typedef float f32x4 __attribute__((ext_vector_type(4)));
using bf16 = __hip_bfloat16;

#define SEQ 2048
#define DM 1024
#define NH 16
#define DH 64
#define NBH 32
#define MR 4096  // B*S

// wait own async loads (vmcnt<=N) then workgroup barrier, as ONE asm block.
#define WAITBAR(N) asm volatile("s_waitcnt vmcnt(" #N ")\n\ts_barrier" ::: "memory")

static __device__ __forceinline__ void async_cp16(const void* gsrc, void* ldsdst) {
  __builtin_amdgcn_global_load_lds((__attribute__((address_space(1))) void*)gsrc,
                                   (__attribute__((address_space(3))) void*)ldsdst, 16, 0, 0);
}

static __device__ __forceinline__ unsigned short f2bfu(float f) {
  bf16 h = __float2bfloat16(f);
  unsigned short u; __builtin_memcpy(&u, &h, 2); return u;
}
static __device__ __forceinline__ unsigned int pack_bf2(float lo, float hi) {
  return (unsigned int)f2bfu(lo) | ((unsigned int)f2bfu(hi) << 16);
}

// ---------------- cast hidden_states to bf16 ----------------
__global__ __launch_bounds__(256) void cast_x(const float* __restrict__ X, bf16* __restrict__ Xb) {
  long g = ((long)blockIdx.x * 256 + threadIdx.x) * 8;
  float4 a = *(const float4*)(X + g);
  float4 b = *(const float4*)(X + g + 4);
  unsigned short u[8];
  u[0]=f2bfu(a.x); u[1]=f2bfu(a.y); u[2]=f2bfu(a.z); u[3]=f2bfu(a.w);
  u[4]=f2bfu(b.x); u[5]=f2bfu(b.y); u[6]=f2bfu(b.z); u[7]=f2bfu(b.w);
  uint4 o; __builtin_memcpy(&o, u, 16);
  *(uint4*)(Xb + g) = o;
}

// ---------------- transpose+cast weights: Wt[n][k] = W[k][n] ----------------
struct WPtrs { const float* w[6]; };

__global__ __launch_bounds__(256) void transpose_cast_w(WPtrs wp, bf16* __restrict__ WtAll) {
  const int z = blockIdx.z;
  const float* W = wp.w[z];
  bf16* Wt = WtAll + (long)z * DM * DM;
  __shared__ float Ts[32][33];
  int n0 = blockIdx.x * 32, k0 = blockIdx.y * 32;
  int tx = threadIdx.x, ty = threadIdx.y;
#pragma unroll
  for (int it = 0; it < 4; ++it)
    Ts[ty + 8*it][tx] = W[(long)(k0 + ty + 8*it) * DM + n0 + tx];
  __syncthreads();
#pragma unroll
  for (int it = 0; it < 4; ++it)
    Wt[(long)(n0 + ty + 8*it) * DM + k0 + tx] = __float2bfloat16(Ts[tx][ty + 8*it]);
}

// ---------------- projection GEMM: heterogeneous grid, zero tail ----------------
struct ProjArgs {
  const float* bias[5];
  bf16* out[5];
};

__global__ __launch_bounds__(256, 2) void gemm_proj(const bf16* __restrict__ A,
                                                    const bf16* __restrict__ WtAll, ProjArgs p) {
  __shared__ alignas(16) bf16 SM[36864];   // 72KB: As 3x[128][32] | Bs 3x[256][32]
  bf16* As = SM;
  bf16* Bs = SM + 12288;
  const int tid = threadIdx.x;
  const int bid = blockIdx.x;              // 1024 = 512 fat + 512 thin
  const int wave = tid >> 6, lane = tid & 63, l15 = lane & 15, l4 = lane >> 4;
  const int wm = wave >> 1, wn = wave & 1;
  const int slot8 = (l4 ^ ((l15 >> 1) & 3)) * 8;
  const int prow = tid >> 2;
  const int cc = (tid & 3) ^ ((prow >> 1) & 3);
  char* dA = (char*)As + wave * 1024;
  char* dB = (char*)Bs + wave * 1024;

  if (bid < 512) {
    // ================= FAT: 128x256 over z = 0..3 =================
    const int mt = bid & 31, nt = bid >> 5;  // nt 0..15
    const int m0 = mt * 128;
    const int z = nt >> 2;
    const int n0z = (nt & 3) * 256;
    const bf16* Bt = WtAll + (long)z * DM * DM + (long)n0z * DM;

    const bf16* sA0 = A  + (long)(m0 + prow) * DM + cc * 8;
    const bf16* sA1 = sA0 + 64L * DM;
    const bf16* sB0 = Bt + (long)prow * DM + cc * 8;
    const bf16* sB1 = sB0 + 64L * DM;
    const bf16* sB2 = sB0 + 128L * DM;
    const bf16* sB3 = sB0 + 192L * DM;

#define PSTAGE(KT_, BUF_) do {                                  \
    int ko_ = (KT_) * 32;                                       \
    async_cp16(sA0 + ko_, dA + (BUF_) * 8192);                  \
    async_cp16(sA1 + ko_, dA + (BUF_) * 8192 + 4096);           \
    async_cp16(sB0 + ko_, dB + (BUF_) * 16384);                 \
    async_cp16(sB1 + ko_, dB + (BUF_) * 16384 + 4096);          \
    async_cp16(sB2 + ko_, dB + (BUF_) * 16384 + 8192);          \
    async_cp16(sB3 + ko_, dB + (BUF_) * 16384 + 12288);         \
  } while (0)

    const int arow = wm * 64 + l15;
    const int brow = wn * 128 + l15;
    f32x4 acc[4][8] = {};

#define PCOMPUTE(BUF_) do {                                                        \
    const bf16* ab_ = As + (BUF_) * 4096;                                          \
    const bf16* bb_ = Bs + (BUF_) * 8192;                                          \
    bf16x8 af_[4], bq_[8];                                                         \
    _Pragma("unroll")                                                              \
    for (int i = 0; i < 4; ++i) af_[i] = *(const bf16x8*)(ab_ + (arow + i * 16) * 32 + slot8); \
    _Pragma("unroll")                                                              \
    for (int j = 0; j < 8; ++j) bq_[j] = *(const bf16x8*)(bb_ + (brow + j * 16) * 32 + slot8); \
    _Pragma("unroll")                                                              \
    for (int i = 0; i < 4; ++i)                                                    \
      _Pragma("unroll")                                                            \
      for (int j = 0; j < 8; ++j)                                                  \
        acc[i][j] = __builtin_amdgcn_mfma_f32_16x16x32_bf16(af_[i], bq_[j], acc[i][j], 0, 0, 0); \
  } while (0)

    PSTAGE(0, 0);
    PSTAGE(1, 1);
    int buf = 0;
#pragma unroll 1
    for (int k = 0; k < 31; ++k) {
      WAITBAR(6);            // own stage(k) landed (stage(k+1)'s 6 ops in flight)
      if (k < 30) {
        int nb = buf + 2; if (nb > 2) nb -= 3;
        PSTAGE(k + 2, nb);
      }
      PCOMPUTE(buf);
      ++buf; if (buf > 2) buf = 0;
    }
    WAITBAR(0);
    PCOMPUTE(buf);
#undef PSTAGE
#undef PCOMPUTE

    // -------- epilogue (fat) --------
    const float* bias = p.bias[z];
    bf16* out = p.out[z];
    float bv[8];
#pragma unroll
    for (int j = 0; j < 8; ++j) bv[j] = bias[n0z + wn * 128 + j * 16 + l15];

    if (z < 2) {
      const float scale = (z == 0) ? 0.125f * 1.44269504f : 1.0f;
#pragma unroll
      for (int i = 0; i < 4; ++i)
#pragma unroll
        for (int j = 0; j < 8; ++j)
#pragma unroll
          for (int r = 0; r < 4; ++r) {
            int m = m0 + wm * 64 + i * 16 + l4 * 4 + r;
            int n = n0z + wn * 128 + j * 16 + l15;
            int b = m >> 11, s = m & 2047, hh = n >> 6, d = n & 63;
            out[((long)((b * NH + hh) * SEQ + s)) * DH + d] =
                __float2bfloat16((acc[i][j][r] + bv[j]) * scale);
          }
    } else {
      // transposed [BH][DH][S] via LDS bounce -> 256B-contiguous stores per thread
      __syncthreads();
      bf16* Os = SM;                           // [256 n][136 stride]
#pragma unroll
      for (int i = 0; i < 4; ++i)
#pragma unroll
        for (int j = 0; j < 8; ++j)
#pragma unroll
          for (int r = 0; r < 4; ++r) {
            int nl = wn * 128 + j * 16 + l15;
            int ml = wm * 64 + i * 16 + l4 * 4 + r;
            Os[nl * 136 + ml] = __float2bfloat16(acc[i][j][r] + bv[j]);
          }
      __syncthreads();
      {
        int nl = tid;
        int ng = n0z + nl;
        int hh = ng >> 6, d = ng & 63;
        int b = m0 >> 11, s0 = m0 & 2047;
        bf16* op = out + ((long)((b * NH + hh) * DH + d)) * SEQ + s0;
#pragma unroll
        for (int u = 0; u < 16; ++u)
          *(bf16x8*)(op + u * 8) = *(const bf16x8*)(Os + nl * 136 + u * 8);
      }
    }
  } else {
    // ================= THIN: 128x64 over v2 (z=4) =================
    const int tb = bid - 512;
    const int mt = tb & 31, nt16 = tb >> 5;   // 0..15
    const int m0 = mt * 128, n0 = nt16 * 64;
    const bf16* Bt = WtAll + 4L * DM * DM + (long)n0 * DM;

    const bf16* sA0 = A + (long)(m0 + prow) * DM + cc * 8;
    const bf16* sA1 = sA0 + 64L * DM;
    const bf16* sB0 = Bt + (long)prow * DM + cc * 8;   // prow 0..63 covers all 64 rows

#define TSTAGE(KT_, BUF_) do {                                  \
    int ko_ = (KT_) * 32;                                       \
    async_cp16(sA0 + ko_, dA + (BUF_) * 8192);                  \
    async_cp16(sA1 + ko_, dA + (BUF_) * 8192 + 4096);           \
    async_cp16(sB0 + ko_, dB + (BUF_) * 4096);                  \
  } while (0)

    const int arow = wm * 64 + l15;
    const int brow = wn * 32 + l15;
    f32x4 acc2[4][2] = {};

#define TCOMPUTE(BUF_) do {                                                        \
    const bf16* ab_ = As + (BUF_) * 4096;                                          \
    const bf16* bb_ = Bs + (BUF_) * 2048;                                          \
    bf16x8 af_[4], bq_[2];                                                         \
    _Pragma("unroll")                                                              \
    for (int i = 0; i < 4; ++i) af_[i] = *(const bf16x8*)(ab_ + (arow + i * 16) * 32 + slot8); \
    _Pragma("unroll")                                                              \
    for (int j = 0; j < 2; ++j) bq_[j] = *(const bf16x8*)(bb_ + (brow + j * 16) * 32 + slot8); \
    _Pragma("unroll")                                                              \
    for (int i = 0; i < 4; ++i)                                                    \
      _Pragma("unroll")                                                            \
      for (int j = 0; j < 2; ++j)                                                  \
        acc2[i][j] = __builtin_amdgcn_mfma_f32_16x16x32_bf16(af_[i], bq_[j], acc2[i][j], 0, 0, 0); \
  } while (0)

    TSTAGE(0, 0);
    TSTAGE(1, 1);
    int buf = 0;
#pragma unroll 1
    for (int k = 0; k < 31; ++k) {
      WAITBAR(3);            // own stage(k)'s 3 loads landed (stage(k+1) in flight)
      if (k < 30) {
        int nb = buf + 2; if (nb > 2) nb -= 3;
        TSTAGE(k + 2, nb);
      }
      TCOMPUTE(buf);
      ++buf; if (buf > 2) buf = 0;
    }
    WAITBAR(0);
    TCOMPUTE(buf);
#undef TSTAGE
#undef TCOMPUTE

    // -------- epilogue (thin, transposed [BH][DH][S]) --------
    float bv2[2];
#pragma unroll
    for (int j = 0; j < 2; ++j) bv2[j] = p.bias[4][n0 + wn * 32 + j * 16 + l15];
    __syncthreads();
    bf16* Os = SM;                             // [64][136] = 17KB
#pragma unroll
    for (int i = 0; i < 4; ++i)
#pragma unroll
      for (int j = 0; j < 2; ++j)
#pragma unroll
        for (int r = 0; r < 4; ++r) {
          int nl = wn * 32 + j * 16 + l15;
          int ml = wm * 64 + i * 16 + l4 * 4 + r;
          Os[nl * 136 + ml] = __float2bfloat16(acc2[i][j][r] + bv2[j]);
        }
    __syncthreads();
    {
      int nl = tid & 63, seg = tid >> 6;       // 4 segs x 32 elems
      int ng = n0 + nl;
      int hh = ng >> 6, d = ng & 63;
      int b = m0 >> 11, s0 = m0 & 2047;
      bf16* op = p.out[4] + ((long)((b * NH + hh) * DH + d)) * SEQ + s0 + seg * 32;
#pragma unroll
      for (int u = 0; u < 4; ++u)
        *(bf16x8*)(op + u * 8) = *(const bf16x8*)(Os + nl * 136 + seg * 32 + u * 8);
    }
  }
}

// ---------------- final GEMM: 128x64 tiles, 512 blocks (2/CU), ring-3 ----------------
__global__ __launch_bounds__(256, 3) void gemm_out(const bf16* __restrict__ A, const bf16* __restrict__ Bt,
                                                   const float* __restrict__ bias, float* __restrict__ out) {
  __shared__ alignas(16) bf16 As[3 * 128 * 32];  // 24KB
  __shared__ alignas(16) bf16 Bs[3 * 64 * 32];   // 12KB
  const int tid = threadIdx.x;
  const int bid = blockIdx.x;            // 512 = 16 n x 32 m
  const int nt = bid & 15, mt = bid >> 4;
  const int m0 = mt * 128, n0 = nt * 64;
  const int wave = tid >> 6, lane = tid & 63, l15 = lane & 15, l4 = lane >> 4;
  const int wm = wave >> 1, wn = wave & 1;
  const int slot8 = (l4 ^ ((l15 >> 1) & 3)) * 8;
  const int prow = tid >> 2;
  const int cc = (tid & 3) ^ ((prow >> 1) & 3);
  const bf16* sA0 = A + (long)(m0 + prow) * DM + cc * 8;
  const bf16* sA1 = sA0 + 64L * DM;
  const bf16* sB0 = Bt + (long)(n0 + prow) * DM + cc * 8;  // prow 0..63 covers the 64 n-rows
  char* dA = (char*)As + wave * 1024;
  char* dB = (char*)Bs + wave * 1024;

#define OSTAGE(KT_, BUF_) do {                                  \
    int ko_ = (KT_) * 32;                                       \
    async_cp16(sA0 + ko_, dA + (BUF_) * 8192);                  \
    async_cp16(sA1 + ko_, dA + (BUF_) * 8192 + 4096);           \
    async_cp16(sB0 + ko_, dB + (BUF_) * 4096);                  \
  } while (0)

  const int arow = wm * 64 + l15;
  const int brow = wn * 32 + l15;
  f32x4 acc2[4][2] = {};

#define OCOMPUTE(BUF_) do {                                                        \
    const bf16* ab_ = As + (BUF_) * 4096;                                          \
    const bf16* bb_ = Bs + (BUF_) * 2048;                                          \
    bf16x8 af_[4], bq_[2];                                                         \
    _Pragma("unroll")                                                              \
    for (int i = 0; i < 4; ++i) af_[i] = *(const bf16x8*)(ab_ + (arow + i * 16) * 32 + slot8); \
    _Pragma("unroll")                                                              \
    for (int j = 0; j < 2; ++j) bq_[j] = *(const bf16x8*)(bb_ + (brow + j * 16) * 32 + slot8); \
    _Pragma("unroll")                                                              \
    for (int i = 0; i < 4; ++i)                                                    \
      _Pragma("unroll")                                                            \
      for (int j = 0; j < 2; ++j)                                                  \
        acc2[i][j] = __builtin_amdgcn_mfma_f32_16x16x32_bf16(af_[i], bq_[j], acc2[i][j], 0, 0, 0); \
  } while (0)

  OSTAGE(0, 0);
  OSTAGE(1, 1);
  int buf = 0;
#pragma unroll 1
  for (int k = 0; k < 31; ++k) {
    WAITBAR(3);
    if (k < 30) {
      int nb = buf + 2; if (nb > 2) nb -= 3;
      OSTAGE(k + 2, nb);
    }
    OCOMPUTE(buf);
    ++buf; if (buf > 2) buf = 0;
  }
  WAITBAR(0);
  OCOMPUTE(buf);
#undef OSTAGE
#undef OCOMPUTE

  float bv[2];
#pragma unroll
  for (int j = 0; j < 2; ++j) bv[j] = bias[n0 + wn * 32 + j * 16 + l15];
#pragma unroll
  for (int i = 0; i < 4; ++i)
#pragma unroll
    for (int j = 0; j < 2; ++j)
#pragma unroll
      for (int r = 0; r < 4; ++r) {
        int m = m0 + wm * 64 + i * 16 + l4 * 4 + r;
        int n = n0 + wn * 32 + j * 16 + l15;
        out[(long)m * DM + n] = acc2[i][j][r] + bv[j];
      }
}

// ---------------- M[b,h] = k2^T v2  (64x64 per head, f32 atomics) ----------------
__global__ __launch_bounds__(256) void m_kernel(
    const bf16* __restrict__ k2t, const bf16* __restrict__ v2t, float* __restrict__ Mbuf)
{
  const int scx = blockIdx.x;  // s chunk 0..7 (256 each)
  const int bh = blockIdx.y;
  const int tid = threadIdx.x, wave = tid >> 6, lane = tid & 63, l15 = lane & 15, l4 = lane >> 4;
  const bf16* kp = k2t + (long)bh * DH * SEQ;
  const bf16* vp = v2t + (long)bh * DH * SEQ;
  __shared__ alignas(16) bf16 K2s[64 * 32];
  __shared__ alignas(16) bf16 V2s[64 * 32];
  f32x4 acc[4] = {};
  const int s0 = scx * 256;
  for (int kk = 0; kk < 256; kk += 32) {
    __syncthreads();
    {
      int c = tid, r = c >> 2, pp = c & 3;
      async_cp16(kp + (long)r * SEQ + s0 + kk + pp * 8, K2s + wave * 64 * 8);
      async_cp16(vp + (long)r * SEQ + s0 + kk + pp * 8, V2s + wave * 64 * 8);
    }
    __syncthreads();
    int arow = 16 * wave + l15;
    bf16x8 a = *(const bf16x8*)(K2s + arow * 32 + l4 * 8);
#pragma unroll
    for (int nb = 0; nb < 4; ++nb) {
      int col = nb * 16 + l15;
      bf16x8 b = *(const bf16x8*)(V2s + col * 32 + l4 * 8);
      acc[nb] = __builtin_amdgcn_mfma_f32_16x16x32_bf16(a, b, acc[nb], 0, 0, 0);
    }
  }
  float* Mp = Mbuf + (long)bh * 4096;
#pragma unroll
  for (int nb = 0; nb < 4; ++nb)
#pragma unroll
    for (int r = 0; r < 4; ++r) {
      int row = 16 * wave + l4 * 4 + r;
      int col = nb * 16 + l15;
      atomicAdd(Mp + row * 64 + col, acc[nb][r]);
    }
}

// -------- cross-lane redistribution: acc layout -> B-frag layout ----------
static __device__ __forceinline__ void redist(const unsigned int (&pk)[4][2], bf16x8 (&pb)[2],
                                              int l4, int l15) {
#pragma unroll
  for (int h = 0; h < 2; ++h) {
    unsigned int w4[4];
#pragma unroll
    for (int w = 0; w < 4; ++w) {
      int src = l15 + 16 * (2 * (l4 & 1) + (w >> 1));
      unsigned int va = (unsigned int)__shfl((int)pk[2 * h][w & 1], src);
      unsigned int vb = (unsigned int)__shfl((int)pk[2 * h + 1][w & 1], src);
      w4[w] = (l4 & 2) ? vb : va;
    }
    __builtin_memcpy(&pb[h], w4, 16);
  }
}

// ---------------- fused flash attention + ctx2: paired q-tiles, KVBLK=128 ----------------
// XCD-aware mapping (T1) + s_setprio around MFMA clusters (T5, m191) +
// exact defer-max (round-9 proven: skip rescale when sf==1).
__global__ __launch_bounds__(256) void attn_fused(
    const bf16* __restrict__ q,    // [BH][S][DH], pre-scaled by log2e/8
    const bf16* __restrict__ k1,   // [BH][S][DH]
    const bf16* __restrict__ v1t,  // [BH][DH][S]
    const float* __restrict__ Mbuf,// [BH][64][64]
    bf16* __restrict__ ctx2)       // [B][S][DM]
{
  const int bid = blockIdx.x;      // 0..511
  const int xcd = bid & 7, ii = bid >> 3;
  const int bh = (xcd << 2) | (ii & 3);    // head group per XCD
  const int qpair = ii >> 2;               // 0..15
  const int bb = bh >> 4, hh = bh & 15;
  const int tid = threadIdx.x, wave = tid >> 6, lane = tid & 63;
  const int l15 = lane & 15, l4 = lane >> 4;
  const bf16* qp = q   + (long)bh * SEQ * DH;
  const bf16* kp = k1  + (long)bh * SEQ * DH;
  const bf16* vp = v1t + (long)bh * DH * SEQ;
  const float* Mp = Mbuf + (long)bh * 4096;

  __shared__ alignas(16) bf16 Ks[2][128 * 64];   // [kv][d], 8 chunks/row, phys = c ^ (kv&7)
  __shared__ alignas(16) bf16 Vs[2][64 * 128];   // [d][kv], 16 chunks/row, phys = c ^ (d&15)

  bf16x8 mf[4][2];
#pragma unroll
  for (int db = 0; db < 4; ++db)
#pragma unroll
    for (int h = 0; h < 2; ++h) {
      bf16x8 t;
#pragma unroll
      for (int j = 0; j < 8; ++j)
        t[j] = (__bf16)Mp[(32 * h + 8 * l4 + j) * 64 + 16 * db + l15];
      mf[db][h] = t;
    }

#define STAGE_KV(JJ, BUF) do {                                                     \
    int kv0_ = 128 * (JJ);                                                         \
    int cK_ = (tid & 7) ^ ((tid >> 3) & 7);                                        \
    int cV_ = (tid & 15) ^ ((tid >> 4) & 15);                                      \
    _Pragma("unroll")                                                              \
    for (int p_ = 0; p_ < 4; ++p_) {                                               \
      int rK_ = (tid >> 3) + 32 * p_;                                              \
      async_cp16(kp + (long)(kv0_ + rK_) * DH + cK_ * 8,                           \
                 (char*)Ks[BUF] + p_ * 4096 + wave * 1024);                        \
      int rV_ = (tid >> 4) + 16 * p_;                                              \
      async_cp16(vp + (long)rV_ * SEQ + kv0_ + cV_ * 8,                            \
                 (char*)Vs[BUF] + p_ * 4096 + wave * 1024);                        \
    }                                                                              \
  } while (0)

#pragma unroll 1
  for (int half = 0; half < 2; ++half) {
    const int tq = (half == 0) ? (31 - qpair) : qpair;   // big tile first
    const int Q0 = 64 * tq;
    const int qg = Q0 + 16 * wave + l15;
    const int jm = tq >> 1;          // last 128-kv tile index

    __syncthreads();                 // prev half's epilogue LDS reads done
    STAGE_KV(0, 0);

    bf16x8 aq[2];
#pragma unroll
    for (int h = 0; h < 2; ++h)
      aq[h] = *(const bf16x8*)(qp + (long)qg * DH + 32 * h + 8 * l4);

    float m_run = -__builtin_inff(), l_run = 0.f;
    f32x4 acc_o[4] = {};

    __syncthreads();                 // stage(0) drained

#pragma unroll 1
    for (int j = 0; j <= jm; ++j) {
      const int cur = j & 1;
      if (j < jm) STAGE_KV(j + 1, cur ^ 1);

      // ---- QK^T (swapped): sc[nb] rows = kv (16nb+..), cols = q ----
      f32x4 sc[8] = {};
      __builtin_amdgcn_s_setprio(1);
#pragma unroll
      for (int nb = 0; nb < 8; ++nb) {
        const bf16* krow = Ks[cur] + (16 * nb + l15) * 64;
#pragma unroll
        for (int h = 0; h < 2; ++h) {
          bf16x8 kf = *(const bf16x8*)(krow + (((4 * h + l4) ^ (l15 & 7)) * 8));
          sc[nb] = __builtin_amdgcn_mfma_f32_16x16x32_bf16(kf, aq[h], sc[nb], 0, 0, 0);
        }
      }
      __builtin_amdgcn_s_setprio(0);

      if (j == jm) {   // diagonal 128-tile: mask kv > q
        const int kv0 = 128 * j;
#pragma unroll
        for (int nb = 0; nb < 8; ++nb)
#pragma unroll
          for (int r = 0; r < 4; ++r)
            if (kv0 + 16 * nb + 4 * l4 + r > qg) sc[nb][r] = -__builtin_inff();
      }

      // ---- softmax (per-lane row, exp2 domain) ----
      float tmax = -__builtin_inff();
#pragma unroll
      for (int nb = 0; nb < 8; ++nb)
#pragma unroll
        for (int r = 0; r < 4; ++r) tmax = fmaxf(tmax, sc[nb][r]);
      tmax = fmaxf(tmax, __shfl_xor(tmax, 16));
      tmax = fmaxf(tmax, __shfl_xor(tmax, 32));

      if (!__all(tmax <= m_run)) {   // exact defer-max: skipped branch has sf == 1
        float mnew = fmaxf(m_run, tmax);
        float sf = __builtin_amdgcn_exp2f(m_run - mnew);
        m_run = mnew;
        l_run *= sf;
#pragma unroll
        for (int db = 0; db < 4; ++db)
#pragma unroll
          for (int r = 0; r < 4; ++r) acc_o[db][r] *= sf;
      }

      float ssum = 0.f;
      unsigned int pkA[4][2], pkB[4][2];
#pragma unroll
      for (int nb = 0; nb < 4; ++nb)
#pragma unroll
        for (int pr = 0; pr < 2; ++pr) {
          float p0 = __builtin_amdgcn_exp2f(sc[nb][2 * pr]     - m_run);
          float p1 = __builtin_amdgcn_exp2f(sc[nb][2 * pr + 1] - m_run);
          ssum += p0 + p1;
          pkA[nb][pr] = pack_bf2(p0, p1);
        }
#pragma unroll
      for (int nb = 0; nb < 4; ++nb)
#pragma unroll
        for (int pr = 0; pr < 2; ++pr) {
          float p0 = __builtin_amdgcn_exp2f(sc[nb + 4][2 * pr]     - m_run);
          float p1 = __builtin_amdgcn_exp2f(sc[nb + 4][2 * pr + 1] - m_run);
          ssum += p0 + p1;
          pkB[nb][pr] = pack_bf2(p0, p1);
        }
      ssum += __shfl_xor(ssum, 16);
      ssum += __shfl_xor(ssum, 32);
      l_run += ssum;

      // ---- P -> B-frag layout (two 64-kv halves), then PV over 4 kv-slices ----
      bf16x8 pbA[2], pbB[2];
      redist(pkA, pbA, l4, l15);
      redist(pkB, pbB, l4, l15);
      __builtin_amdgcn_s_setprio(1);
#pragma unroll
      for (int db = 0; db < 4; ++db) {
        const bf16* vrow = Vs[cur] + (16 * db + l15) * 128;
#pragma unroll
        for (int hs = 0; hs < 2; ++hs) {
          bf16x8 vf = *(const bf16x8*)(vrow + (((4 * hs + l4) ^ l15) * 8));
          acc_o[db] = __builtin_amdgcn_mfma_f32_16x16x32_bf16(vf, pbA[hs], acc_o[db], 0, 0, 0);
        }
#pragma unroll
        for (int hs = 0; hs < 2; ++hs) {
          bf16x8 vf = *(const bf16x8*)(vrow + (((4 * (hs + 2) + l4) ^ l15) * 8));
          acc_o[db] = __builtin_amdgcn_mfma_f32_16x16x32_bf16(vf, pbB[hs], acc_o[db], 0, 0, 0);
        }
      }
      __builtin_amdgcn_s_setprio(0);
      __syncthreads();   // staged tile j+1 drained; buffers swappable
    }

    // ---- epilogue: ctx1 = acc/l ; ctx2_tile = ctx1 @ M  (8 MFMA) ----
    float invl = __builtin_amdgcn_rcpf(l_run);
    unsigned int ck[4][2];
#pragma unroll
    for (int db = 0; db < 4; ++db)
#pragma unroll
      for (int pr = 0; pr < 2; ++pr)
        ck[db][pr] = pack_bf2(acc_o[db][2 * pr] * invl, acc_o[db][2 * pr + 1] * invl);
    bf16x8 cb[2];
    redist(ck, cb, l4, l15);
    f32x4 o2[4] = {};
#pragma unroll
    for (int db = 0; db < 4; ++db)
#pragma unroll
      for (int h = 0; h < 2; ++h)
        o2[db] = __builtin_amdgcn_mfma_f32_16x16x32_bf16(mf[db][h], cb[h], o2[db], 0, 0, 0);

    // o2: row = d' = 16db+4*l4+r, col = q = l15 -> transpose via padded LDS, store coalesced
    bf16* Os = (bf16*)Ks;   // 64 x 72 pad = 9216 elems, fits easily
#pragma unroll
    for (int db = 0; db < 4; ++db)
#pragma unroll
      for (int r = 0; r < 4; ++r)
        Os[(16 * wave + l15) * 72 + 16 * db + 4 * l4 + r] = __float2bfloat16(o2[db][r]);
    __syncthreads();
    {
      int rr = tid >> 2, cc2 = tid & 3;
      long obase = ((long)(bb * SEQ + Q0 + rr)) * DM + hh * DH + cc2 * 16;
      *(bf16x8*)(ctx2 + obase)     = *(const bf16x8*)(Os + rr * 72 + cc2 * 16);
      *(bf16x8*)(ctx2 + obase + 8) = *(const bf16x8*)(Os + rr * 72 + cc2 * 16 + 8);
    }
  }
#undef STAGE_KV
}

// ---------------- launch ----------------
extern "C" void kernel_launch(void* const* d_in, const int* in_sizes, int n_in,
                              void* d_out, int out_size, void* d_ws, size_t ws_size,
                              hipStream_t stream) {
  (void)in_sizes; (void)n_in; (void)out_size; (void)ws_size;
  const float* X = (const float*)d_in[0];
  const float* W[6]    = {(const float*)d_in[1], (const float*)d_in[3], (const float*)d_in[5],
                          (const float*)d_in[7], (const float*)d_in[9], (const float*)d_in[11]};
  const float* bias[6] = {(const float*)d_in[2], (const float*)d_in[4], (const float*)d_in[6],
                          (const float*)d_in[8], (const float*)d_in[10], (const float*)d_in[12]};

  char* ws = (char*)d_ws;
  bf16* Xb  = (bf16*)(ws);                 // 8 MB (reused as ctx2 after proj GEMM done)
  bf16* Wt  = (bf16*)(ws + (8L  << 20));   // 12 MB (6 x 2MB)
  bf16* qB  = (bf16*)(ws + (20L << 20));   // 8 MB  [BH][S][DH]
  bf16* k1B = (bf16*)(ws + (28L << 20));   // 8 MB  [BH][S][DH]
  bf16* k2t = (bf16*)(ws + (36L << 20));   // 8 MB  [BH][DH][S]
  bf16* v1t = (bf16*)(ws + (44L << 20));   // 8 MB  [BH][DH][S]
  bf16* v2t = (bf16*)(ws + (52L << 20));   // 8 MB  [BH][DH][S]
  float* Mb = (float*)(ws + (60L << 20));  // 512 KB
  bf16* c2  = Xb;                          // reuse: ctx2 [4096][1024]

  cast_x<<<2048, 256, 0, stream>>>(X, Xb);

  WPtrs wp; for (int z = 0; z < 6; ++z) wp.w[z] = W[z];
  transpose_cast_w<<<dim3(32, 32, 6), dim3(32, 8), 0, stream>>>(wp, Wt);

  ProjArgs pa;
  for (int z = 0; z < 5; ++z) pa.bias[z] = bias[z];
  pa.out[0] = qB; pa.out[1] = k1B; pa.out[2] = k2t; pa.out[3] = v1t; pa.out[4] = v2t;
  gemm_proj<<<1024, 256, 0, stream>>>(Xb, Wt, pa);

  hipMemsetAsync(Mb, 0, (size_t)NBH * 4096 * 4, stream);
  m_kernel<<<dim3(8, 32), 256, 0, stream>>>(k2t, v2t, Mb);

  attn_fused<<<512, 256, 0, stream>>>(qB, k1B, v1t, Mb, c2);

  gemm_out<<<512, 256, 0, stream>>>(c2, Wt + 5L * DM * DM, bias[5], (float*)d_out);
}

// Round 20
// 141.973 us; speedup vs baseline: 1.0355x; 1.0314x over previous
//
#include <hip/hip_runtime.h>
#include <hip/hip_bf16.h>

typedef __bf16 bf16x8 __attribute__((ext_vector_type(8)));
typedef float f32x4 __attribute__((ext_vector_type(4)));
using bf16 = __hip_bfloat16;

#define SEQ 2048
#define DM 1024
#define NH 16
#define DH 64
#define NBH 32
#define MR 4096  // B*S

// wait own async loads (vmcnt<=N) then workgroup barrier, as ONE asm block.
#define WAITBAR(N) asm volatile("s_waitcnt vmcnt(" #N ")\n\ts_barrier" ::: "memory")

static __device__ __forceinline__ void async_cp16(const void* gsrc, void* ldsdst) {
  __builtin_amdgcn_global_load_lds((__attribute__((address_space(1))) void*)gsrc,
                                   (__attribute__((address_space(3))) void*)ldsdst, 16, 0, 0);
}

static __device__ __forceinline__ unsigned short f2bfu(float f) {
  bf16 h = __float2bfloat16(f);
  unsigned short u; __builtin_memcpy(&u, &h, 2); return u;
}
static __device__ __forceinline__ unsigned int pack_bf2(float lo, float hi) {
  return (unsigned int)f2bfu(lo) | ((unsigned int)f2bfu(hi) << 16);
}

// ---------------- fused prep: weight transpose+cast (z<6), X cast (z>=6), Mb zero ----------
struct WPtrs { const float* w[6]; };

__global__ __launch_bounds__(256) void prep(WPtrs wp, const float* __restrict__ X,
                                            bf16* __restrict__ WtAll, bf16* __restrict__ Xb,
                                            float* __restrict__ Mb) {
  __shared__ float Ts[32][33];
  const int z = blockIdx.z;
  const int tid = threadIdx.x;
  if (z < 6) {
    // transpose+cast weight z: Wt[n][k] = W[k][n]
    const float* W = wp.w[z];
    bf16* Wt = WtAll + (long)z * DM * DM;
    const int n0 = blockIdx.x * 32, k0 = blockIdx.y * 32;
    const int tx = tid & 31, ty = tid >> 5;
#pragma unroll
    for (int it = 0; it < 4; ++it)
      Ts[ty + 8 * it][tx] = W[(long)(k0 + ty + 8 * it) * DM + n0 + tx];
    __syncthreads();
#pragma unroll
    for (int it = 0; it < 4; ++it)
      Wt[(long)(n0 + ty + 8 * it) * DM + k0 + tx] = __float2bfloat16(Ts[tx][ty + 8 * it]);
    if (z == 0 && tid < 32) {    // zero Mb: 1024 blocks x 128 floats = 512KB
      int lin = blockIdx.x + 32 * blockIdx.y;
      f32x4 zz = {0.f, 0.f, 0.f, 0.f};
      *(f32x4*)(Mb + lin * 128 + tid * 4) = zz;
    }
  } else {
    // cast X -> bf16: slices z=6,7 cover 2 x 1024 blocks x 2048 floats
    int lin = blockIdx.x + 32 * blockIdx.y + (z - 6) * 1024;
    long g = (long)lin * 2048 + tid * 8;
    float4 a = *(const float4*)(X + g);
    float4 b = *(const float4*)(X + g + 4);
    unsigned short u[8];
    u[0]=f2bfu(a.x); u[1]=f2bfu(a.y); u[2]=f2bfu(a.z); u[3]=f2bfu(a.w);
    u[4]=f2bfu(b.x); u[5]=f2bfu(b.y); u[6]=f2bfu(b.z); u[7]=f2bfu(b.w);
    uint4 o; __builtin_memcpy(&o, u, 16);
    *(uint4*)(Xb + g) = o;
  }
}

// ---------------- projection GEMM: heterogeneous grid, zero tail ----------------
struct ProjArgs {
  const float* bias[5];
  bf16* out[5];
};

__global__ __launch_bounds__(256, 2) void gemm_proj(const bf16* __restrict__ A,
                                                    const bf16* __restrict__ WtAll, ProjArgs p) {
  __shared__ alignas(16) bf16 SM[36864];   // 72KB: As 3x[128][32] | Bs 3x[256][32]
  bf16* As = SM;
  bf16* Bs = SM + 12288;
  const int tid = threadIdx.x;
  const int bid = blockIdx.x;              // 1024 = 512 fat + 512 thin
  const int wave = tid >> 6, lane = tid & 63, l15 = lane & 15, l4 = lane >> 4;
  const int wm = wave >> 1, wn = wave & 1;
  const int slot8 = (l4 ^ ((l15 >> 1) & 3)) * 8;
  const int prow = tid >> 2;
  const int cc = (tid & 3) ^ ((prow >> 1) & 3);
  char* dA = (char*)As + wave * 1024;
  char* dB = (char*)Bs + wave * 1024;

  if (bid < 512) {
    // ================= FAT: 128x256 over z = 0..3 =================
    const int mt = bid & 31, nt = bid >> 5;  // nt 0..15
    const int m0 = mt * 128;
    const int z = nt >> 2;
    const int n0z = (nt & 3) * 256;
    const bf16* Bt = WtAll + (long)z * DM * DM + (long)n0z * DM;

    const bf16* sA0 = A  + (long)(m0 + prow) * DM + cc * 8;
    const bf16* sA1 = sA0 + 64L * DM;
    const bf16* sB0 = Bt + (long)prow * DM + cc * 8;
    const bf16* sB1 = sB0 + 64L * DM;
    const bf16* sB2 = sB0 + 128L * DM;
    const bf16* sB3 = sB0 + 192L * DM;

#define PSTAGE(KT_, BUF_) do {                                  \
    int ko_ = (KT_) * 32;                                       \
    async_cp16(sA0 + ko_, dA + (BUF_) * 8192);                  \
    async_cp16(sA1 + ko_, dA + (BUF_) * 8192 + 4096);           \
    async_cp16(sB0 + ko_, dB + (BUF_) * 16384);                 \
    async_cp16(sB1 + ko_, dB + (BUF_) * 16384 + 4096);          \
    async_cp16(sB2 + ko_, dB + (BUF_) * 16384 + 8192);          \
    async_cp16(sB3 + ko_, dB + (BUF_) * 16384 + 12288);         \
  } while (0)

    const int arow = wm * 64 + l15;
    const int brow = wn * 128 + l15;
    f32x4 acc[4][8] = {};

#define PCOMPUTE(BUF_) do {                                                        \
    const bf16* ab_ = As + (BUF_) * 4096;                                          \
    const bf16* bb_ = Bs + (BUF_) * 8192;                                          \
    bf16x8 af_[4], bq_[8];                                                         \
    _Pragma("unroll")                                                              \
    for (int i = 0; i < 4; ++i) af_[i] = *(const bf16x8*)(ab_ + (arow + i * 16) * 32 + slot8); \
    _Pragma("unroll")                                                              \
    for (int j = 0; j < 8; ++j) bq_[j] = *(const bf16x8*)(bb_ + (brow + j * 16) * 32 + slot8); \
    _Pragma("unroll")                                                              \
    for (int i = 0; i < 4; ++i)                                                    \
      _Pragma("unroll")                                                            \
      for (int j = 0; j < 8; ++j)                                                  \
        acc[i][j] = __builtin_amdgcn_mfma_f32_16x16x32_bf16(af_[i], bq_[j], acc[i][j], 0, 0, 0); \
  } while (0)

    PSTAGE(0, 0);
    PSTAGE(1, 1);
    int buf = 0;
#pragma unroll 1
    for (int k = 0; k < 31; ++k) {
      WAITBAR(6);            // own stage(k) landed (stage(k+1)'s 6 ops in flight)
      if (k < 30) {
        int nb = buf + 2; if (nb > 2) nb -= 3;
        PSTAGE(k + 2, nb);
      }
      PCOMPUTE(buf);
      ++buf; if (buf > 2) buf = 0;
    }
    WAITBAR(0);
    PCOMPUTE(buf);
#undef PSTAGE
#undef PCOMPUTE

    // -------- epilogue (fat) --------
    const float* bias = p.bias[z];
    bf16* out = p.out[z];
    float bv[8];
#pragma unroll
    for (int j = 0; j < 8; ++j) bv[j] = bias[n0z + wn * 128 + j * 16 + l15];

    if (z < 2) {
      const float scale = (z == 0) ? 0.125f * 1.44269504f : 1.0f;
#pragma unroll
      for (int i = 0; i < 4; ++i)
#pragma unroll
        for (int j = 0; j < 8; ++j)
#pragma unroll
          for (int r = 0; r < 4; ++r) {
            int m = m0 + wm * 64 + i * 16 + l4 * 4 + r;
            int n = n0z + wn * 128 + j * 16 + l15;
            int b = m >> 11, s = m & 2047, hh = n >> 6, d = n & 63;
            out[((long)((b * NH + hh) * SEQ + s)) * DH + d] =
                __float2bfloat16((acc[i][j][r] + bv[j]) * scale);
          }
    } else {
      // transposed [BH][DH][S] via LDS bounce -> 256B-contiguous stores per thread
      __syncthreads();
      bf16* Os = SM;                           // [256 n][136 stride]
#pragma unroll
      for (int i = 0; i < 4; ++i)
#pragma unroll
        for (int j = 0; j < 8; ++j)
#pragma unroll
          for (int r = 0; r < 4; ++r) {
            int nl = wn * 128 + j * 16 + l15;
            int ml = wm * 64 + i * 16 + l4 * 4 + r;
            Os[nl * 136 + ml] = __float2bfloat16(acc[i][j][r] + bv[j]);
          }
      __syncthreads();
      {
        int nl = tid;
        int ng = n0z + nl;
        int hh = ng >> 6, d = ng & 63;
        int b = m0 >> 11, s0 = m0 & 2047;
        bf16* op = out + ((long)((b * NH + hh) * DH + d)) * SEQ + s0;
#pragma unroll
        for (int u = 0; u < 16; ++u)
          *(bf16x8*)(op + u * 8) = *(const bf16x8*)(Os + nl * 136 + u * 8);
      }
    }
  } else {
    // ================= THIN: 128x64 over v2 (z=4) =================
    const int tb = bid - 512;
    const int mt = tb & 31, nt16 = tb >> 5;   // 0..15
    const int m0 = mt * 128, n0 = nt16 * 64;
    const bf16* Bt = WtAll + 4L * DM * DM + (long)n0 * DM;

    const bf16* sA0 = A + (long)(m0 + prow) * DM + cc * 8;
    const bf16* sA1 = sA0 + 64L * DM;
    const bf16* sB0 = Bt + (long)prow * DM + cc * 8;   // prow 0..63 covers all 64 rows

#define TSTAGE(KT_, BUF_) do {                                  \
    int ko_ = (KT_) * 32;                                       \
    async_cp16(sA0 + ko_, dA + (BUF_) * 8192);                  \
    async_cp16(sA1 + ko_, dA + (BUF_) * 8192 + 4096);           \
    async_cp16(sB0 + ko_, dB + (BUF_) * 4096);                  \
  } while (0)

    const int arow = wm * 64 + l15;
    const int brow = wn * 32 + l15;
    f32x4 acc2[4][2] = {};

#define TCOMPUTE(BUF_) do {                                                        \
    const bf16* ab_ = As + (BUF_) * 4096;                                          \
    const bf16* bb_ = Bs + (BUF_) * 2048;                                          \
    bf16x8 af_[4], bq_[2];                                                         \
    _Pragma("unroll")                                                              \
    for (int i = 0; i < 4; ++i) af_[i] = *(const bf16x8*)(ab_ + (arow + i * 16) * 32 + slot8); \
    _Pragma("unroll")                                                              \
    for (int j = 0; j < 2; ++j) bq_[j] = *(const bf16x8*)(bb_ + (brow + j * 16) * 32 + slot8); \
    _Pragma("unroll")                                                              \
    for (int i = 0; i < 4; ++i)                                                    \
      _Pragma("unroll")                                                            \
      for (int j = 0; j < 2; ++j)                                                  \
        acc2[i][j] = __builtin_amdgcn_mfma_f32_16x16x32_bf16(af_[i], bq_[j], acc2[i][j], 0, 0, 0); \
  } while (0)

    TSTAGE(0, 0);
    TSTAGE(1, 1);
    int buf = 0;
#pragma unroll 1
    for (int k = 0; k < 31; ++k) {
      WAITBAR(3);            // own stage(k)'s 3 loads landed (stage(k+1) in flight)
      if (k < 30) {
        int nb = buf + 2; if (nb > 2) nb -= 3;
        TSTAGE(k + 2, nb);
      }
      TCOMPUTE(buf);
      ++buf; if (buf > 2) buf = 0;
    }
    WAITBAR(0);
    TCOMPUTE(buf);
#undef TSTAGE
#undef TCOMPUTE

    // -------- epilogue (thin, transposed [BH][DH][S]) --------
    float bv2[2];
#pragma unroll
    for (int j = 0; j < 2; ++j) bv2[j] = p.bias[4][n0 + wn * 32 + j * 16 + l15];
    __syncthreads();
    bf16* Os = SM;                             // [64][136] = 17KB
#pragma unroll
    for (int i = 0; i < 4; ++i)
#pragma unroll
      for (int j = 0; j < 2; ++j)
#pragma unroll
        for (int r = 0; r < 4; ++r) {
          int nl = wn * 32 + j * 16 + l15;
          int ml = wm * 64 + i * 16 + l4 * 4 + r;
          Os[nl * 136 + ml] = __float2bfloat16(acc2[i][j][r] + bv2[j]);
        }
    __syncthreads();
    {
      int nl = tid & 63, seg = tid >> 6;       // 4 segs x 32 elems
      int ng = n0 + nl;
      int hh = ng >> 6, d = ng & 63;
      int b = m0 >> 11, s0 = m0 & 2047;
      bf16* op = p.out[4] + ((long)((b * NH + hh) * DH + d)) * SEQ + s0 + seg * 32;
#pragma unroll
      for (int u = 0; u < 4; ++u)
        *(bf16x8*)(op + u * 8) = *(const bf16x8*)(Os + nl * 136 + seg * 32 + u * 8);
    }
  }
}

// ---------------- final GEMM: 128x64 tiles, 512 blocks (2/CU), ring-3 ----------------
__global__ __launch_bounds__(256, 3) void gemm_out(const bf16* __restrict__ A, const bf16* __restrict__ Bt,
                                                   const float* __restrict__ bias, float* __restrict__ out) {
  __shared__ alignas(16) bf16 As[3 * 128 * 32];  // 24KB
  __shared__ alignas(16) bf16 Bs[3 * 64 * 32];   // 12KB
  const int tid = threadIdx.x;
  const int bid = blockIdx.x;            // 512 = 16 n x 32 m
  const int nt = bid & 15, mt = bid >> 4;
  const int m0 = mt * 128, n0 = nt * 64;
  const int wave = tid >> 6, lane = tid & 63, l15 = lane & 15, l4 = lane >> 4;
  const int wm = wave >> 1, wn = wave & 1;
  const int slot8 = (l4 ^ ((l15 >> 1) & 3)) * 8;
  const int prow = tid >> 2;
  const int cc = (tid & 3) ^ ((prow >> 1) & 3);
  const bf16* sA0 = A + (long)(m0 + prow) * DM + cc * 8;
  const bf16* sA1 = sA0 + 64L * DM;
  const bf16* sB0 = Bt + (long)(n0 + prow) * DM + cc * 8;  // prow 0..63 covers the 64 n-rows
  char* dA = (char*)As + wave * 1024;
  char* dB = (char*)Bs + wave * 1024;

#define OSTAGE(KT_, BUF_) do {                                  \
    int ko_ = (KT_) * 32;                                       \
    async_cp16(sA0 + ko_, dA + (BUF_) * 8192);                  \
    async_cp16(sA1 + ko_, dA + (BUF_) * 8192 + 4096);           \
    async_cp16(sB0 + ko_, dB + (BUF_) * 4096);                  \
  } while (0)

  const int arow = wm * 64 + l15;
  const int brow = wn * 32 + l15;
  f32x4 acc2[4][2] = {};

#define OCOMPUTE(BUF_) do {                                                        \
    const bf16* ab_ = As + (BUF_) * 4096;                                          \
    const bf16* bb_ = Bs + (BUF_) * 2048;                                          \
    bf16x8 af_[4], bq_[2];                                                         \
    _Pragma("unroll")                                                              \
    for (int i = 0; i < 4; ++i) af_[i] = *(const bf16x8*)(ab_ + (arow + i * 16) * 32 + slot8); \
    _Pragma("unroll")                                                              \
    for (int j = 0; j < 2; ++j) bq_[j] = *(const bf16x8*)(bb_ + (brow + j * 16) * 32 + slot8); \
    _Pragma("unroll")                                                              \
    for (int i = 0; i < 4; ++i)                                                    \
      _Pragma("unroll")                                                            \
      for (int j = 0; j < 2; ++j)                                                  \
        acc2[i][j] = __builtin_amdgcn_mfma_f32_16x16x32_bf16(af_[i], bq_[j], acc2[i][j], 0, 0, 0); \
  } while (0)

  OSTAGE(0, 0);
  OSTAGE(1, 1);
  int buf = 0;
#pragma unroll 1
  for (int k = 0; k < 31; ++k) {
    WAITBAR(3);
    if (k < 30) {
      int nb = buf + 2; if (nb > 2) nb -= 3;
      OSTAGE(k + 2, nb);
    }
    OCOMPUTE(buf);
    ++buf; if (buf > 2) buf = 0;
  }
  WAITBAR(0);
  OCOMPUTE(buf);
#undef OSTAGE
#undef OCOMPUTE

  float bv[2];
#pragma unroll
  for (int j = 0; j < 2; ++j) bv[j] = bias[n0 + wn * 32 + j * 16 + l15];
#pragma unroll
  for (int i = 0; i < 4; ++i)
#pragma unroll
    for (int j = 0; j < 2; ++j)
#pragma unroll
      for (int r = 0; r < 4; ++r) {
        int m = m0 + wm * 64 + i * 16 + l4 * 4 + r;
        int n = n0 + wn * 32 + j * 16 + l15;
        out[(long)m * DM + n] = acc2[i][j][r] + bv[j];
      }
}

// ---------------- M[b,h] = k2^T v2  (64x64 per head, f32 atomics) ----------------
__global__ __launch_bounds__(256) void m_kernel(
    const bf16* __restrict__ k2t, const bf16* __restrict__ v2t, float* __restrict__ Mbuf)
{
  const int scx = blockIdx.x;  // s chunk 0..7 (256 each)
  const int bh = blockIdx.y;
  const int tid = threadIdx.x, wave = tid >> 6, lane = tid & 63, l15 = lane & 15, l4 = lane >> 4;
  const bf16* kp = k2t + (long)bh * DH * SEQ;
  const bf16* vp = v2t + (long)bh * DH * SEQ;
  __shared__ alignas(16) bf16 K2s[64 * 32];
  __shared__ alignas(16) bf16 V2s[64 * 32];
  f32x4 acc[4] = {};
  const int s0 = scx * 256;
  for (int kk = 0; kk < 256; kk += 32) {
    __syncthreads();
    {
      int c = tid, r = c >> 2, pp = c & 3;
      async_cp16(kp + (long)r * SEQ + s0 + kk + pp * 8, K2s + wave * 64 * 8);
      async_cp16(vp + (long)r * SEQ + s0 + kk + pp * 8, V2s + wave * 64 * 8);
    }
    __syncthreads();
    int arow = 16 * wave + l15;
    bf16x8 a = *(const bf16x8*)(K2s + arow * 32 + l4 * 8);
#pragma unroll
    for (int nb = 0; nb < 4; ++nb) {
      int col = nb * 16 + l15;
      bf16x8 b = *(const bf16x8*)(V2s + col * 32 + l4 * 8);
      acc[nb] = __builtin_amdgcn_mfma_f32_16x16x32_bf16(a, b, acc[nb], 0, 0, 0);
    }
  }
  float* Mp = Mbuf + (long)bh * 4096;
#pragma unroll
  for (int nb = 0; nb < 4; ++nb)
#pragma unroll
    for (int r = 0; r < 4; ++r) {
      int row = 16 * wave + l4 * 4 + r;
      int col = nb * 16 + l15;
      atomicAdd(Mp + row * 64 + col, acc[nb][r]);
    }
}

// -------- cross-lane redistribution: acc layout -> B-frag layout ----------
static __device__ __forceinline__ void redist(const unsigned int (&pk)[4][2], bf16x8 (&pb)[2],
                                              int l4, int l15) {
#pragma unroll
  for (int h = 0; h < 2; ++h) {
    unsigned int w4[4];
#pragma unroll
    for (int w = 0; w < 4; ++w) {
      int src = l15 + 16 * (2 * (l4 & 1) + (w >> 1));
      unsigned int va = (unsigned int)__shfl((int)pk[2 * h][w & 1], src);
      unsigned int vb = (unsigned int)__shfl((int)pk[2 * h + 1][w & 1], src);
      w4[w] = (l4 & 2) ? vb : va;
    }
    __builtin_memcpy(&pb[h], w4, 16);
  }
}

// ---------------- fused flash attention + ctx2: paired q-tiles, KVBLK=128 ----------------
// XCD-aware mapping (T1) + s_setprio around MFMA clusters (T5, m191) +
// exact defer-max (round-9 proven: skip rescale when sf==1).
__global__ __launch_bounds__(256) void attn_fused(
    const bf16* __restrict__ q,    // [BH][S][DH], pre-scaled by log2e/8
    const bf16* __restrict__ k1,   // [BH][S][DH]
    const bf16* __restrict__ v1t,  // [BH][DH][S]
    const float* __restrict__ Mbuf,// [BH][64][64]
    bf16* __restrict__ ctx2)       // [B][S][DM]
{
  const int bid = blockIdx.x;      // 0..511
  const int xcd = bid & 7, ii = bid >> 3;
  const int bh = (xcd << 2) | (ii & 3);    // head group per XCD
  const int qpair = ii >> 2;               // 0..15
  const int bb = bh >> 4, hh = bh & 15;
  const int tid = threadIdx.x, wave = tid >> 6, lane = tid & 63;
  const int l15 = lane & 15, l4 = lane >> 4;
  const bf16* qp = q   + (long)bh * SEQ * DH;
  const bf16* kp = k1  + (long)bh * SEQ * DH;
  const bf16* vp = v1t + (long)bh * DH * SEQ;
  const float* Mp = Mbuf + (long)bh * 4096;

  __shared__ alignas(16) bf16 Ks[2][128 * 64];   // [kv][d], 8 chunks/row, phys = c ^ (kv&7)
  __shared__ alignas(16) bf16 Vs[2][64 * 128];   // [d][kv], 16 chunks/row, phys = c ^ (d&15)

  bf16x8 mf[4][2];
#pragma unroll
  for (int db = 0; db < 4; ++db)
#pragma unroll
    for (int h = 0; h < 2; ++h) {
      bf16x8 t;
#pragma unroll
      for (int j = 0; j < 8; ++j)
        t[j] = (__bf16)Mp[(32 * h + 8 * l4 + j) * 64 + 16 * db + l15];
      mf[db][h] = t;
    }

#define STAGE_KV(JJ, BUF) do {                                                     \
    int kv0_ = 128 * (JJ);                                                         \
    int cK_ = (tid & 7) ^ ((tid >> 3) & 7);                                        \
    int cV_ = (tid & 15) ^ ((tid >> 4) & 15);                                      \
    _Pragma("unroll")                                                              \
    for (int p_ = 0; p_ < 4; ++p_) {                                               \
      int rK_ = (tid >> 3) + 32 * p_;                                              \
      async_cp16(kp + (long)(kv0_ + rK_) * DH + cK_ * 8,                           \
                 (char*)Ks[BUF] + p_ * 4096 + wave * 1024);                        \
      int rV_ = (tid >> 4) + 16 * p_;                                              \
      async_cp16(vp + (long)rV_ * SEQ + kv0_ + cV_ * 8,                            \
                 (char*)Vs[BUF] + p_ * 4096 + wave * 1024);                        \
    }                                                                              \
  } while (0)

#pragma unroll 1
  for (int half = 0; half < 2; ++half) {
    const int tq = (half == 0) ? (31 - qpair) : qpair;   // big tile first
    const int Q0 = 64 * tq;
    const int qg = Q0 + 16 * wave + l15;
    const int jm = tq >> 1;          // last 128-kv tile index

    __syncthreads();                 // prev half's epilogue LDS reads done
    STAGE_KV(0, 0);

    bf16x8 aq[2];
#pragma unroll
    for (int h = 0; h < 2; ++h)
      aq[h] = *(const bf16x8*)(qp + (long)qg * DH + 32 * h + 8 * l4);

    float m_run = -__builtin_inff(), l_run = 0.f;
    f32x4 acc_o[4] = {};

    __syncthreads();                 // stage(0) drained

#pragma unroll 1
    for (int j = 0; j <= jm; ++j) {
      const int cur = j & 1;
      if (j < jm) STAGE_KV(j + 1, cur ^ 1);

      // ---- QK^T (swapped): sc[nb] rows = kv (16nb+..), cols = q ----
      f32x4 sc[8] = {};
      __builtin_amdgcn_s_setprio(1);
#pragma unroll
      for (int nb = 0; nb < 8; ++nb) {
        const bf16* krow = Ks[cur] + (16 * nb + l15) * 64;
#pragma unroll
        for (int h = 0; h < 2; ++h) {
          bf16x8 kf = *(const bf16x8*)(krow + (((4 * h + l4) ^ (l15 & 7)) * 8));
          sc[nb] = __builtin_amdgcn_mfma_f32_16x16x32_bf16(kf, aq[h], sc[nb], 0, 0, 0);
        }
      }
      __builtin_amdgcn_s_setprio(0);

      if (j == jm) {   // diagonal 128-tile: mask kv > q
        const int kv0 = 128 * j;
#pragma unroll
        for (int nb = 0; nb < 8; ++nb)
#pragma unroll
          for (int r = 0; r < 4; ++r)
            if (kv0 + 16 * nb + 4 * l4 + r > qg) sc[nb][r] = -__builtin_inff();
      }

      // ---- softmax (per-lane row, exp2 domain) ----
      float tmax = -__builtin_inff();
#pragma unroll
      for (int nb = 0; nb < 8; ++nb)
#pragma unroll
        for (int r = 0; r < 4; ++r) tmax = fmaxf(tmax, sc[nb][r]);
      tmax = fmaxf(tmax, __shfl_xor(tmax, 16));
      tmax = fmaxf(tmax, __shfl_xor(tmax, 32));

      if (!__all(tmax <= m_run)) {   // exact defer-max: skipped branch has sf == 1
        float mnew = fmaxf(m_run, tmax);
        float sf = __builtin_amdgcn_exp2f(m_run - mnew);
        m_run = mnew;
        l_run *= sf;
#pragma unroll
        for (int db = 0; db < 4; ++db)
#pragma unroll
          for (int r = 0; r < 4; ++r) acc_o[db][r] *= sf;
      }

      float ssum = 0.f;
      unsigned int pkA[4][2], pkB[4][2];
#pragma unroll
      for (int nb = 0; nb < 4; ++nb)
#pragma unroll
        for (int pr = 0; pr < 2; ++pr) {
          float p0 = __builtin_amdgcn_exp2f(sc[nb][2 * pr]     - m_run);
          float p1 = __builtin_amdgcn_exp2f(sc[nb][2 * pr + 1] - m_run);
          ssum += p0 + p1;
          pkA[nb][pr] = pack_bf2(p0, p1);
        }
#pragma unroll
      for (int nb = 0; nb < 4; ++nb)
#pragma unroll
        for (int pr = 0; pr < 2; ++pr) {
          float p0 = __builtin_amdgcn_exp2f(sc[nb + 4][2 * pr]     - m_run);
          float p1 = __builtin_amdgcn_exp2f(sc[nb + 4][2 * pr + 1] - m_run);
          ssum += p0 + p1;
          pkB[nb][pr] = pack_bf2(p0, p1);
        }
      ssum += __shfl_xor(ssum, 16);
      ssum += __shfl_xor(ssum, 32);
      l_run += ssum;

      // ---- P -> B-frag layout (two 64-kv halves), then PV over 4 kv-slices ----
      bf16x8 pbA[2], pbB[2];
      redist(pkA, pbA, l4, l15);
      redist(pkB, pbB, l4, l15);
      __builtin_amdgcn_s_setprio(1);
#pragma unroll
      for (int db = 0; db < 4; ++db) {
        const bf16* vrow = Vs[cur] + (16 * db + l15) * 128;
#pragma unroll
        for (int hs = 0; hs < 2; ++hs) {
          bf16x8 vf = *(const bf16x8*)(vrow + (((4 * hs + l4) ^ l15) * 8));
          acc_o[db] = __builtin_amdgcn_mfma_f32_16x16x32_bf16(vf, pbA[hs], acc_o[db], 0, 0, 0);
        }
#pragma unroll
        for (int hs = 0; hs < 2; ++hs) {
          bf16x8 vf = *(const bf16x8*)(vrow + (((4 * (hs + 2) + l4) ^ l15) * 8));
          acc_o[db] = __builtin_amdgcn_mfma_f32_16x16x32_bf16(vf, pbB[hs], acc_o[db], 0, 0, 0);
        }
      }
      __builtin_amdgcn_s_setprio(0);
      __syncthreads();   // staged tile j+1 drained; buffers swappable
    }

    // ---- epilogue: ctx1 = acc/l ; ctx2_tile = ctx1 @ M  (8 MFMA) ----
    float invl = __builtin_amdgcn_rcpf(l_run);
    unsigned int ck[4][2];
#pragma unroll
    for (int db = 0; db < 4; ++db)
#pragma unroll
      for (int pr = 0; pr < 2; ++pr)
        ck[db][pr] = pack_bf2(acc_o[db][2 * pr] * invl, acc_o[db][2 * pr + 1] * invl);
    bf16x8 cb[2];
    redist(ck, cb, l4, l15);
    f32x4 o2[4] = {};
#pragma unroll
    for (int db = 0; db < 4; ++db)
#pragma unroll
      for (int h = 0; h < 2; ++h)
        o2[db] = __builtin_amdgcn_mfma_f32_16x16x32_bf16(mf[db][h], cb[h], o2[db], 0, 0, 0);

    // o2: row = d' = 16db+4*l4+r, col = q = l15 -> transpose via padded LDS, store coalesced
    bf16* Os = (bf16*)Ks;   // 64 x 72 pad = 9216 elems, fits easily
#pragma unroll
    for (int db = 0; db < 4; ++db)
#pragma unroll
      for (int r = 0; r < 4; ++r)
        Os[(16 * wave + l15) * 72 + 16 * db + 4 * l4 + r] = __float2bfloat16(o2[db][r]);
    __syncthreads();
    {
      int rr = tid >> 2, cc2 = tid & 3;
      long obase = ((long)(bb * SEQ + Q0 + rr)) * DM + hh * DH + cc2 * 16;
      *(bf16x8*)(ctx2 + obase)     = *(const bf16x8*)(Os + rr * 72 + cc2 * 16);
      *(bf16x8*)(ctx2 + obase + 8) = *(const bf16x8*)(Os + rr * 72 + cc2 * 16 + 8);
    }
  }
#undef STAGE_KV
}

// ---------------- launch ----------------
extern "C" void kernel_launch(void* const* d_in, const int* in_sizes, int n_in,
                              void* d_out, int out_size, void* d_ws, size_t ws_size,
                              hipStream_t stream) {
  (void)in_sizes; (void)n_in; (void)out_size; (void)ws_size;
  const float* X = (const float*)d_in[0];
  const float* W[6]    = {(const float*)d_in[1], (const float*)d_in[3], (const float*)d_in[5],
                          (const float*)d_in[7], (const float*)d_in[9], (const float*)d_in[11]};
  const float* bias[6] = {(const float*)d_in[2], (const float*)d_in[4], (const float*)d_in[6],
                          (const float*)d_in[8], (const float*)d_in[10], (const float*)d_in[12]};

  char* ws = (char*)d_ws;
  bf16* Xb  = (bf16*)(ws);                 // 8 MB (reused as ctx2 after proj GEMM done)
  bf16* Wt  = (bf16*)(ws + (8L  << 20));   // 12 MB (6 x 2MB)
  bf16* qB  = (bf16*)(ws + (20L << 20));   // 8 MB  [BH][S][DH]
  bf16* k1B = (bf16*)(ws + (28L << 20));   // 8 MB  [BH][S][DH]
  bf16* k2t = (bf16*)(ws + (36L << 20));   // 8 MB  [BH][DH][S]
  bf16* v1t = (bf16*)(ws + (44L << 20));   // 8 MB  [BH][DH][S]
  bf16* v2t = (bf16*)(ws + (52L << 20));   // 8 MB  [BH][DH][S]
  float* Mb = (float*)(ws + (60L << 20));  // 512 KB
  bf16* c2  = Xb;                          // reuse: ctx2 [4096][1024]

  WPtrs wp; for (int z = 0; z < 6; ++z) wp.w[z] = W[z];
  prep<<<dim3(32, 32, 8), 256, 0, stream>>>(wp, X, Wt, Xb, Mb);

  ProjArgs pa;
  for (int z = 0; z < 5; ++z) pa.bias[z] = bias[z];
  pa.out[0] = qB; pa.out[1] = k1B; pa.out[2] = k2t; pa.out[3] = v1t; pa.out[4] = v2t;
  gemm_proj<<<1024, 256, 0, stream>>>(Xb, Wt, pa);

  m_kernel<<<dim3(8, 32), 256, 0, stream>>>(k2t, v2t, Mb);

  attn_fused<<<512, 256, 0, stream>>>(qB, k1B, v1t, Mb, c2);

  gemm_out<<<512, 256, 0, stream>>>(c2, Wt + 5L * DM * DM, bias[5], (float*)d_out);
}

// Round 21
// 141.646 us; speedup vs baseline: 1.0379x; 1.0023x over previous
//
#include <hip/hip_runtime.h>
#include <hip/hip_bf16.h>

typedef __bf16 bf16x8 __attribute__((ext_vector_type(8)));
typedef float f32x4 __attribute__((ext_vector_type(4)));
using bf16 = __hip_bfloat16;

#define SEQ 2048
#define DM 1024
#define NH 16
#define DH 64
#define NBH 32
#define MR 4096  // B*S

// wait own async loads (vmcnt<=N) then workgroup barrier, as ONE asm block.
#define WAITBAR(N) asm volatile("s_waitcnt vmcnt(" #N ")\n\ts_barrier" ::: "memory")

static __device__ __forceinline__ void async_cp16(const void* gsrc, void* ldsdst) {
  __builtin_amdgcn_global_load_lds((__attribute__((address_space(1))) void*)gsrc,
                                   (__attribute__((address_space(3))) void*)ldsdst, 16, 0, 0);
}

static __device__ __forceinline__ unsigned short f2bfu(float f) {
  bf16 h = __float2bfloat16(f);
  unsigned short u; __builtin_memcpy(&u, &h, 2); return u;
}
static __device__ __forceinline__ unsigned int pack_bf2(float lo, float hi) {
  return (unsigned int)f2bfu(lo) | ((unsigned int)f2bfu(hi) << 16);
}

// ---------------- fused prep: weight transpose+cast (z<6), X cast (z>=6), Mb zero ----------
struct WPtrs { const float* w[6]; };

__global__ __launch_bounds__(256) void prep(WPtrs wp, const float* __restrict__ X,
                                            bf16* __restrict__ WtAll, bf16* __restrict__ Xb,
                                            float* __restrict__ Mb) {
  __shared__ float Ts[32][33];
  const int z = blockIdx.z;
  const int tid = threadIdx.x;
  if (z < 6) {
    // transpose+cast weight z: Wt[n][k] = W[k][n]
    const float* W = wp.w[z];
    bf16* Wt = WtAll + (long)z * DM * DM;
    const int n0 = blockIdx.x * 32, k0 = blockIdx.y * 32;
    const int tx = tid & 31, ty = tid >> 5;
#pragma unroll
    for (int it = 0; it < 4; ++it)
      Ts[ty + 8 * it][tx] = W[(long)(k0 + ty + 8 * it) * DM + n0 + tx];
    __syncthreads();
#pragma unroll
    for (int it = 0; it < 4; ++it)
      Wt[(long)(n0 + ty + 8 * it) * DM + k0 + tx] = __float2bfloat16(Ts[tx][ty + 8 * it]);
    if (z == 0 && tid < 32) {    // zero Mb: 1024 blocks x 128 floats = 512KB
      int lin = blockIdx.x + 32 * blockIdx.y;
      f32x4 zz = {0.f, 0.f, 0.f, 0.f};
      *(f32x4*)(Mb + lin * 128 + tid * 4) = zz;
    }
  } else {
    // cast X -> bf16: slices z=6,7 cover 2 x 1024 blocks x 2048 floats
    int lin = blockIdx.x + 32 * blockIdx.y + (z - 6) * 1024;
    long g = (long)lin * 2048 + tid * 8;
    float4 a = *(const float4*)(X + g);
    float4 b = *(const float4*)(X + g + 4);
    unsigned short u[8];
    u[0]=f2bfu(a.x); u[1]=f2bfu(a.y); u[2]=f2bfu(a.z); u[3]=f2bfu(a.w);
    u[4]=f2bfu(b.x); u[5]=f2bfu(b.y); u[6]=f2bfu(b.z); u[7]=f2bfu(b.w);
    uint4 o; __builtin_memcpy(&o, u, 16);
    *(uint4*)(Xb + g) = o;
  }
}

// ---------------- projection GEMM: heterogeneous grid, zero tail ----------------
struct ProjArgs {
  const float* bias[5];
  bf16* out[5];
};

__global__ __launch_bounds__(256, 2) void gemm_proj(const bf16* __restrict__ A,
                                                    const bf16* __restrict__ WtAll, ProjArgs p) {
  __shared__ alignas(16) bf16 SM[36864];   // 72KB: As 3x[128][32] | Bs 3x[256][32]
  bf16* As = SM;
  bf16* Bs = SM + 12288;
  const int tid = threadIdx.x;
  const int bid = blockIdx.x;              // 1024 = 512 fat + 512 thin
  const int wave = tid >> 6, lane = tid & 63, l15 = lane & 15, l4 = lane >> 4;
  const int wm = wave >> 1, wn = wave & 1;
  const int slot8 = (l4 ^ ((l15 >> 1) & 3)) * 8;
  const int prow = tid >> 2;
  const int cc = (tid & 3) ^ ((prow >> 1) & 3);
  char* dA = (char*)As + wave * 1024;
  char* dB = (char*)Bs + wave * 1024;

  if (bid < 512) {
    // ================= FAT: 128x256 over z = 0..3 =================
    const int mt = bid & 31, nt = bid >> 5;  // nt 0..15
    const int m0 = mt * 128;
    const int z = nt >> 2;
    const int n0z = (nt & 3) * 256;
    const bf16* Bt = WtAll + (long)z * DM * DM + (long)n0z * DM;

    const bf16* sA0 = A  + (long)(m0 + prow) * DM + cc * 8;
    const bf16* sA1 = sA0 + 64L * DM;
    const bf16* sB0 = Bt + (long)prow * DM + cc * 8;
    const bf16* sB1 = sB0 + 64L * DM;
    const bf16* sB2 = sB0 + 128L * DM;
    const bf16* sB3 = sB0 + 192L * DM;

#define PSTAGE(KT_, BUF_) do {                                  \
    int ko_ = (KT_) * 32;                                       \
    async_cp16(sA0 + ko_, dA + (BUF_) * 8192);                  \
    async_cp16(sA1 + ko_, dA + (BUF_) * 8192 + 4096);           \
    async_cp16(sB0 + ko_, dB + (BUF_) * 16384);                 \
    async_cp16(sB1 + ko_, dB + (BUF_) * 16384 + 4096);          \
    async_cp16(sB2 + ko_, dB + (BUF_) * 16384 + 8192);          \
    async_cp16(sB3 + ko_, dB + (BUF_) * 16384 + 12288);         \
  } while (0)

    const int arow = wm * 64 + l15;
    const int brow = wn * 128 + l15;
    f32x4 acc[4][8] = {};

#define PCOMPUTE(BUF_) do {                                                        \
    const bf16* ab_ = As + (BUF_) * 4096;                                          \
    const bf16* bb_ = Bs + (BUF_) * 8192;                                          \
    bf16x8 af_[4], bq_[8];                                                         \
    _Pragma("unroll")                                                              \
    for (int i = 0; i < 4; ++i) af_[i] = *(const bf16x8*)(ab_ + (arow + i * 16) * 32 + slot8); \
    _Pragma("unroll")                                                              \
    for (int j = 0; j < 8; ++j) bq_[j] = *(const bf16x8*)(bb_ + (brow + j * 16) * 32 + slot8); \
    _Pragma("unroll")                                                              \
    for (int i = 0; i < 4; ++i)                                                    \
      _Pragma("unroll")                                                            \
      for (int j = 0; j < 8; ++j)                                                  \
        acc[i][j] = __builtin_amdgcn_mfma_f32_16x16x32_bf16(af_[i], bq_[j], acc[i][j], 0, 0, 0); \
  } while (0)

    PSTAGE(0, 0);
    PSTAGE(1, 1);
    int buf = 0;
#pragma unroll 1
    for (int k = 0; k < 31; ++k) {
      WAITBAR(6);            // own stage(k) landed (stage(k+1)'s 6 ops in flight)
      if (k < 30) {
        int nb = buf + 2; if (nb > 2) nb -= 3;
        PSTAGE(k + 2, nb);
      }
      PCOMPUTE(buf);
      ++buf; if (buf > 2) buf = 0;
    }
    WAITBAR(0);
    PCOMPUTE(buf);
#undef PSTAGE
#undef PCOMPUTE

    // -------- epilogue (fat) --------
    const float* bias = p.bias[z];
    bf16* out = p.out[z];
    float bv[8];
#pragma unroll
    for (int j = 0; j < 8; ++j) bv[j] = bias[n0z + wn * 128 + j * 16 + l15];

    if (z < 2) {
      const float scale = (z == 0) ? 0.125f * 1.44269504f : 1.0f;
#pragma unroll
      for (int i = 0; i < 4; ++i)
#pragma unroll
        for (int j = 0; j < 8; ++j)
#pragma unroll
          for (int r = 0; r < 4; ++r) {
            int m = m0 + wm * 64 + i * 16 + l4 * 4 + r;
            int n = n0z + wn * 128 + j * 16 + l15;
            int b = m >> 11, s = m & 2047, hh = n >> 6, d = n & 63;
            out[((long)((b * NH + hh) * SEQ + s)) * DH + d] =
                __float2bfloat16((acc[i][j][r] + bv[j]) * scale);
          }
    } else {
      // transposed [BH][DH][S] via LDS bounce -> 256B-contiguous stores per thread
      __syncthreads();
      bf16* Os = SM;                           // [256 n][136 stride]
#pragma unroll
      for (int i = 0; i < 4; ++i)
#pragma unroll
        for (int j = 0; j < 8; ++j)
#pragma unroll
          for (int r = 0; r < 4; ++r) {
            int nl = wn * 128 + j * 16 + l15;
            int ml = wm * 64 + i * 16 + l4 * 4 + r;
            Os[nl * 136 + ml] = __float2bfloat16(acc[i][j][r] + bv[j]);
          }
      __syncthreads();
      {
        int nl = tid;
        int ng = n0z + nl;
        int hh = ng >> 6, d = ng & 63;
        int b = m0 >> 11, s0 = m0 & 2047;
        bf16* op = out + ((long)((b * NH + hh) * DH + d)) * SEQ + s0;
#pragma unroll
        for (int u = 0; u < 16; ++u)
          *(bf16x8*)(op + u * 8) = *(const bf16x8*)(Os + nl * 136 + u * 8);
      }
    }
  } else {
    // ================= THIN: 128x64 over v2 (z=4) =================
    const int tb = bid - 512;
    const int mt = tb & 31, nt16 = tb >> 5;   // 0..15
    const int m0 = mt * 128, n0 = nt16 * 64;
    const bf16* Bt = WtAll + 4L * DM * DM + (long)n0 * DM;

    const bf16* sA0 = A + (long)(m0 + prow) * DM + cc * 8;
    const bf16* sA1 = sA0 + 64L * DM;
    const bf16* sB0 = Bt + (long)prow * DM + cc * 8;   // prow 0..63 covers all 64 rows

#define TSTAGE(KT_, BUF_) do {                                  \
    int ko_ = (KT_) * 32;                                       \
    async_cp16(sA0 + ko_, dA + (BUF_) * 8192);                  \
    async_cp16(sA1 + ko_, dA + (BUF_) * 8192 + 4096);           \
    async_cp16(sB0 + ko_, dB + (BUF_) * 4096);                  \
  } while (0)

    const int arow = wm * 64 + l15;
    const int brow = wn * 32 + l15;
    f32x4 acc2[4][2] = {};

#define TCOMPUTE(BUF_) do {                                                        \
    const bf16* ab_ = As + (BUF_) * 4096;                                          \
    const bf16* bb_ = Bs + (BUF_) * 2048;                                          \
    bf16x8 af_[4], bq_[2];                                                         \
    _Pragma("unroll")                                                              \
    for (int i = 0; i < 4; ++i) af_[i] = *(const bf16x8*)(ab_ + (arow + i * 16) * 32 + slot8); \
    _Pragma("unroll")                                                              \
    for (int j = 0; j < 2; ++j) bq_[j] = *(const bf16x8*)(bb_ + (brow + j * 16) * 32 + slot8); \
    _Pragma("unroll")                                                              \
    for (int i = 0; i < 4; ++i)                                                    \
      _Pragma("unroll")                                                            \
      for (int j = 0; j < 2; ++j)                                                  \
        acc2[i][j] = __builtin_amdgcn_mfma_f32_16x16x32_bf16(af_[i], bq_[j], acc2[i][j], 0, 0, 0); \
  } while (0)

    TSTAGE(0, 0);
    TSTAGE(1, 1);
    int buf = 0;
#pragma unroll 1
    for (int k = 0; k < 31; ++k) {
      WAITBAR(3);            // own stage(k)'s 3 loads landed (stage(k+1) in flight)
      if (k < 30) {
        int nb = buf + 2; if (nb > 2) nb -= 3;
        TSTAGE(k + 2, nb);
      }
      TCOMPUTE(buf);
      ++buf; if (buf > 2) buf = 0;
    }
    WAITBAR(0);
    TCOMPUTE(buf);
#undef TSTAGE
#undef TCOMPUTE

    // -------- epilogue (thin, transposed [BH][DH][S]) --------
    float bv2[2];
#pragma unroll
    for (int j = 0; j < 2; ++j) bv2[j] = p.bias[4][n0 + wn * 32 + j * 16 + l15];
    __syncthreads();
    bf16* Os = SM;                             // [64][136] = 17KB
#pragma unroll
    for (int i = 0; i < 4; ++i)
#pragma unroll
      for (int j = 0; j < 2; ++j)
#pragma unroll
        for (int r = 0; r < 4; ++r) {
          int nl = wn * 32 + j * 16 + l15;
          int ml = wm * 64 + i * 16 + l4 * 4 + r;
          Os[nl * 136 + ml] = __float2bfloat16(acc2[i][j][r] + bv2[j]);
        }
    __syncthreads();
    {
      int nl = tid & 63, seg = tid >> 6;       // 4 segs x 32 elems
      int ng = n0 + nl;
      int hh = ng >> 6, d = ng & 63;
      int b = m0 >> 11, s0 = m0 & 2047;
      bf16* op = p.out[4] + ((long)((b * NH + hh) * DH + d)) * SEQ + s0 + seg * 32;
#pragma unroll
      for (int u = 0; u < 4; ++u)
        *(bf16x8*)(op + u * 8) = *(const bf16x8*)(Os + nl * 136 + seg * 32 + u * 8);
    }
  }
}

// ---------------- final GEMM: 128x64 tiles, 512 blocks (2/CU), ring-3 ----------------
__global__ __launch_bounds__(256, 3) void gemm_out(const bf16* __restrict__ A, const bf16* __restrict__ Bt,
                                                   const float* __restrict__ bias, float* __restrict__ out) {
  __shared__ alignas(16) bf16 As[3 * 128 * 32];  // 24KB
  __shared__ alignas(16) bf16 Bs[3 * 64 * 32];   // 12KB
  const int tid = threadIdx.x;
  const int bid = blockIdx.x;            // 512 = 16 n x 32 m
  const int nt = bid & 15, mt = bid >> 4;
  const int m0 = mt * 128, n0 = nt * 64;
  const int wave = tid >> 6, lane = tid & 63, l15 = lane & 15, l4 = lane >> 4;
  const int wm = wave >> 1, wn = wave & 1;
  const int slot8 = (l4 ^ ((l15 >> 1) & 3)) * 8;
  const int prow = tid >> 2;
  const int cc = (tid & 3) ^ ((prow >> 1) & 3);
  const bf16* sA0 = A + (long)(m0 + prow) * DM + cc * 8;
  const bf16* sA1 = sA0 + 64L * DM;
  const bf16* sB0 = Bt + (long)(n0 + prow) * DM + cc * 8;  // prow 0..63 covers the 64 n-rows
  char* dA = (char*)As + wave * 1024;
  char* dB = (char*)Bs + wave * 1024;

#define OSTAGE(KT_, BUF_) do {                                  \
    int ko_ = (KT_) * 32;                                       \
    async_cp16(sA0 + ko_, dA + (BUF_) * 8192);                  \
    async_cp16(sA1 + ko_, dA + (BUF_) * 8192 + 4096);           \
    async_cp16(sB0 + ko_, dB + (BUF_) * 4096);                  \
  } while (0)

  const int arow = wm * 64 + l15;
  const int brow = wn * 32 + l15;
  f32x4 acc2[4][2] = {};

#define OCOMPUTE(BUF_) do {                                                        \
    const bf16* ab_ = As + (BUF_) * 4096;                                          \
    const bf16* bb_ = Bs + (BUF_) * 2048;                                          \
    bf16x8 af_[4], bq_[2];                                                         \
    _Pragma("unroll")                                                              \
    for (int i = 0; i < 4; ++i) af_[i] = *(const bf16x8*)(ab_ + (arow + i * 16) * 32 + slot8); \
    _Pragma("unroll")                                                              \
    for (int j = 0; j < 2; ++j) bq_[j] = *(const bf16x8*)(bb_ + (brow + j * 16) * 32 + slot8); \
    _Pragma("unroll")                                                              \
    for (int i = 0; i < 4; ++i)                                                    \
      _Pragma("unroll")                                                            \
      for (int j = 0; j < 2; ++j)                                                  \
        acc2[i][j] = __builtin_amdgcn_mfma_f32_16x16x32_bf16(af_[i], bq_[j], acc2[i][j], 0, 0, 0); \
  } while (0)

  OSTAGE(0, 0);
  OSTAGE(1, 1);
  int buf = 0;
#pragma unroll 1
  for (int k = 0; k < 31; ++k) {
    WAITBAR(3);
    if (k < 30) {
      int nb = buf + 2; if (nb > 2) nb -= 3;
      OSTAGE(k + 2, nb);
    }
    OCOMPUTE(buf);
    ++buf; if (buf > 2) buf = 0;
  }
  WAITBAR(0);
  OCOMPUTE(buf);
#undef OSTAGE
#undef OCOMPUTE

  float bv[2];
#pragma unroll
  for (int j = 0; j < 2; ++j) bv[j] = bias[n0 + wn * 32 + j * 16 + l15];
#pragma unroll
  for (int i = 0; i < 4; ++i)
#pragma unroll
    for (int j = 0; j < 2; ++j)
#pragma unroll
      for (int r = 0; r < 4; ++r) {
        int m = m0 + wm * 64 + i * 16 + l4 * 4 + r;
        int n = n0 + wn * 32 + j * 16 + l15;
        out[(long)m * DM + n] = acc2[i][j][r] + bv[j];
      }
}

// ---------------- M[b,h] = k2^T v2: ring-3 staged 64-col chunks, counted vmcnt ----------------
// Same verified [64][32] sub-tile read layout as before; barriers 16 -> 5.
__global__ __launch_bounds__(256) void m_kernel(
    const bf16* __restrict__ k2t, const bf16* __restrict__ v2t, float* __restrict__ Mbuf)
{
  const int scx = blockIdx.x;  // s chunk 0..7 (256 each)
  const int bh = blockIdx.y;
  const int tid = threadIdx.x, wave = tid >> 6, lane = tid & 63, l15 = lane & 15, l4 = lane >> 4;
  const bf16* kp = k2t + (long)bh * DH * SEQ;
  const bf16* vp = v2t + (long)bh * DH * SEQ;
  __shared__ alignas(16) bf16 K2s[3][2][64 * 32];   // 24KB: ring-3 x 2 sub-tiles
  __shared__ alignas(16) bf16 V2s[3][2][64 * 32];   // 24KB
  f32x4 acc[4] = {};
  const int s0 = scx * 256;
  const int rr = tid >> 2, pp = tid & 3;
  const bf16* kb = kp + (long)rr * SEQ + s0 + pp * 8;
  const bf16* vb = vp + (long)rr * SEQ + s0 + pp * 8;

#define MSTAGE(CH_, BUF_) do {                                            \
    int co_ = (CH_) * 64;                                                 \
    async_cp16(kb + co_,      (char*)K2s + (BUF_) * 8192 + wave * 1024);  \
    async_cp16(kb + co_ + 32, (char*)K2s + (BUF_) * 8192 + 4096 + wave * 1024); \
    async_cp16(vb + co_,      (char*)V2s + (BUF_) * 8192 + wave * 1024);  \
    async_cp16(vb + co_ + 32, (char*)V2s + (BUF_) * 8192 + 4096 + wave * 1024); \
  } while (0)

  MSTAGE(0, 0);
  MSTAGE(1, 1);
  int buf = 0;
  const int arow = 16 * wave + l15;
#pragma unroll 1
  for (int c = 0; c < 4; ++c) {
    if (c == 3) { WAITBAR(0); } else { WAITBAR(4); }
    if (c < 2) {
      int nb = buf + 2; if (nb > 2) nb -= 3;
      MSTAGE(c + 2, nb);
    }
#pragma unroll
    for (int sb = 0; sb < 2; ++sb) {
      const bf16* Kb = &K2s[buf][sb][0];
      const bf16* Vb = &V2s[buf][sb][0];
      bf16x8 a = *(const bf16x8*)(Kb + arow * 32 + l4 * 8);
#pragma unroll
      for (int nb2 = 0; nb2 < 4; ++nb2) {
        int col = nb2 * 16 + l15;
        bf16x8 b = *(const bf16x8*)(Vb + col * 32 + l4 * 8);
        acc[nb2] = __builtin_amdgcn_mfma_f32_16x16x32_bf16(a, b, acc[nb2], 0, 0, 0);
      }
    }
    ++buf; if (buf > 2) buf = 0;
  }
#undef MSTAGE

  float* Mp = Mbuf + (long)bh * 4096;
#pragma unroll
  for (int nb2 = 0; nb2 < 4; ++nb2)
#pragma unroll
    for (int r = 0; r < 4; ++r) {
      int row = 16 * wave + l4 * 4 + r;
      int col = nb2 * 16 + l15;
      atomicAdd(Mp + row * 64 + col, acc[nb2][r]);
    }
}

// -------- cross-lane redistribution: acc layout -> B-frag layout ----------
static __device__ __forceinline__ void redist(const unsigned int (&pk)[4][2], bf16x8 (&pb)[2],
                                              int l4, int l15) {
#pragma unroll
  for (int h = 0; h < 2; ++h) {
    unsigned int w4[4];
#pragma unroll
    for (int w = 0; w < 4; ++w) {
      int src = l15 + 16 * (2 * (l4 & 1) + (w >> 1));
      unsigned int va = (unsigned int)__shfl((int)pk[2 * h][w & 1], src);
      unsigned int vb = (unsigned int)__shfl((int)pk[2 * h + 1][w & 1], src);
      w4[w] = (l4 & 2) ? vb : va;
    }
    __builtin_memcpy(&pb[h], w4, 16);
  }
}

// ---------------- fused flash attention + ctx2: paired q-tiles, KVBLK=128 ----------------
// XCD-aware mapping (T1) + s_setprio around MFMA clusters (T5, m191) +
// exact defer-max (round-9 proven: skip rescale when sf==1).
__global__ __launch_bounds__(256) void attn_fused(
    const bf16* __restrict__ q,    // [BH][S][DH], pre-scaled by log2e/8
    const bf16* __restrict__ k1,   // [BH][S][DH]
    const bf16* __restrict__ v1t,  // [BH][DH][S]
    const float* __restrict__ Mbuf,// [BH][64][64]
    bf16* __restrict__ ctx2)       // [B][S][DM]
{
  const int bid = blockIdx.x;      // 0..511
  const int xcd = bid & 7, ii = bid >> 3;
  const int bh = (xcd << 2) | (ii & 3);    // head group per XCD
  const int qpair = ii >> 2;               // 0..15
  const int bb = bh >> 4, hh = bh & 15;
  const int tid = threadIdx.x, wave = tid >> 6, lane = tid & 63;
  const int l15 = lane & 15, l4 = lane >> 4;
  const bf16* qp = q   + (long)bh * SEQ * DH;
  const bf16* kp = k1  + (long)bh * SEQ * DH;
  const bf16* vp = v1t + (long)bh * DH * SEQ;
  const float* Mp = Mbuf + (long)bh * 4096;

  __shared__ alignas(16) bf16 Ks[2][128 * 64];   // [kv][d], 8 chunks/row, phys = c ^ (kv&7)
  __shared__ alignas(16) bf16 Vs[2][64 * 128];   // [d][kv], 16 chunks/row, phys = c ^ (d&15)

  bf16x8 mf[4][2];
#pragma unroll
  for (int db = 0; db < 4; ++db)
#pragma unroll
    for (int h = 0; h < 2; ++h) {
      bf16x8 t;
#pragma unroll
      for (int j = 0; j < 8; ++j)
        t[j] = (__bf16)Mp[(32 * h + 8 * l4 + j) * 64 + 16 * db + l15];
      mf[db][h] = t;
    }

#define STAGE_KV(JJ, BUF) do {                                                     \
    int kv0_ = 128 * (JJ);                                                         \
    int cK_ = (tid & 7) ^ ((tid >> 3) & 7);                                        \
    int cV_ = (tid & 15) ^ ((tid >> 4) & 15);                                      \
    _Pragma("unroll")                                                              \
    for (int p_ = 0; p_ < 4; ++p_) {                                               \
      int rK_ = (tid >> 3) + 32 * p_;                                              \
      async_cp16(kp + (long)(kv0_ + rK_) * DH + cK_ * 8,                           \
                 (char*)Ks[BUF] + p_ * 4096 + wave * 1024);                        \
      int rV_ = (tid >> 4) + 16 * p_;                                              \
      async_cp16(vp + (long)rV_ * SEQ + kv0_ + cV_ * 8,                            \
                 (char*)Vs[BUF] + p_ * 4096 + wave * 1024);                        \
    }                                                                              \
  } while (0)

#pragma unroll 1
  for (int half = 0; half < 2; ++half) {
    const int tq = (half == 0) ? (31 - qpair) : qpair;   // big tile first
    const int Q0 = 64 * tq;
    const int qg = Q0 + 16 * wave + l15;
    const int jm = tq >> 1;          // last 128-kv tile index

    __syncthreads();                 // prev half's epilogue LDS reads done
    STAGE_KV(0, 0);

    bf16x8 aq[2];
#pragma unroll
    for (int h = 0; h < 2; ++h)
      aq[h] = *(const bf16x8*)(qp + (long)qg * DH + 32 * h + 8 * l4);

    float m_run = -__builtin_inff(), l_run = 0.f;
    f32x4 acc_o[4] = {};

    __syncthreads();                 // stage(0) drained

#pragma unroll 1
    for (int j = 0; j <= jm; ++j) {
      const int cur = j & 1;
      if (j < jm) STAGE_KV(j + 1, cur ^ 1);

      // ---- QK^T (swapped): sc[nb] rows = kv (16nb+..), cols = q ----
      f32x4 sc[8] = {};
      __builtin_amdgcn_s_setprio(1);
#pragma unroll
      for (int nb = 0; nb < 8; ++nb) {
        const bf16* krow = Ks[cur] + (16 * nb + l15) * 64;
#pragma unroll
        for (int h = 0; h < 2; ++h) {
          bf16x8 kf = *(const bf16x8*)(krow + (((4 * h + l4) ^ (l15 & 7)) * 8));
          sc[nb] = __builtin_amdgcn_mfma_f32_16x16x32_bf16(kf, aq[h], sc[nb], 0, 0, 0);
        }
      }
      __builtin_amdgcn_s_setprio(0);

      if (j == jm) {   // diagonal 128-tile: mask kv > q
        const int kv0 = 128 * j;
#pragma unroll
        for (int nb = 0; nb < 8; ++nb)
#pragma unroll
          for (int r = 0; r < 4; ++r)
            if (kv0 + 16 * nb + 4 * l4 + r > qg) sc[nb][r] = -__builtin_inff();
      }

      // ---- softmax (per-lane row, exp2 domain) ----
      float tmax = -__builtin_inff();
#pragma unroll
      for (int nb = 0; nb < 8; ++nb)
#pragma unroll
        for (int r = 0; r < 4; ++r) tmax = fmaxf(tmax, sc[nb][r]);
      tmax = fmaxf(tmax, __shfl_xor(tmax, 16));
      tmax = fmaxf(tmax, __shfl_xor(tmax, 32));

      if (!__all(tmax <= m_run)) {   // exact defer-max: skipped branch has sf == 1
        float mnew = fmaxf(m_run, tmax);
        float sf = __builtin_amdgcn_exp2f(m_run - mnew);
        m_run = mnew;
        l_run *= sf;
#pragma unroll
        for (int db = 0; db < 4; ++db)
#pragma unroll
          for (int r = 0; r < 4; ++r) acc_o[db][r] *= sf;
      }

      float ssum = 0.f;
      unsigned int pkA[4][2], pkB[4][2];
#pragma unroll
      for (int nb = 0; nb < 4; ++nb)
#pragma unroll
        for (int pr = 0; pr < 2; ++pr) {
          float p0 = __builtin_amdgcn_exp2f(sc[nb][2 * pr]     - m_run);
          float p1 = __builtin_amdgcn_exp2f(sc[nb][2 * pr + 1] - m_run);
          ssum += p0 + p1;
          pkA[nb][pr] = pack_bf2(p0, p1);
        }
#pragma unroll
      for (int nb = 0; nb < 4; ++nb)
#pragma unroll
        for (int pr = 0; pr < 2; ++pr) {
          float p0 = __builtin_amdgcn_exp2f(sc[nb + 4][2 * pr]     - m_run);
          float p1 = __builtin_amdgcn_exp2f(sc[nb + 4][2 * pr + 1] - m_run);
          ssum += p0 + p1;
          pkB[nb][pr] = pack_bf2(p0, p1);
        }
      ssum += __shfl_xor(ssum, 16);
      ssum += __shfl_xor(ssum, 32);
      l_run += ssum;

      // ---- P -> B-frag layout (two 64-kv halves), then PV over 4 kv-slices ----
      bf16x8 pbA[2], pbB[2];
      redist(pkA, pbA, l4, l15);
      redist(pkB, pbB, l4, l15);
      __builtin_amdgcn_s_setprio(1);
#pragma unroll
      for (int db = 0; db < 4; ++db) {
        const bf16* vrow = Vs[cur] + (16 * db + l15) * 128;
#pragma unroll
        for (int hs = 0; hs < 2; ++hs) {
          bf16x8 vf = *(const bf16x8*)(vrow + (((4 * hs + l4) ^ l15) * 8));
          acc_o[db] = __builtin_amdgcn_mfma_f32_16x16x32_bf16(vf, pbA[hs], acc_o[db], 0, 0, 0);
        }
#pragma unroll
        for (int hs = 0; hs < 2; ++hs) {
          bf16x8 vf = *(const bf16x8*)(vrow + (((4 * (hs + 2) + l4) ^ l15) * 8));
          acc_o[db] = __builtin_amdgcn_mfma_f32_16x16x32_bf16(vf, pbB[hs], acc_o[db], 0, 0, 0);
        }
      }
      __builtin_amdgcn_s_setprio(0);
      __syncthreads();   // staged tile j+1 drained; buffers swappable
    }

    // ---- epilogue: ctx1 = acc/l ; ctx2_tile = ctx1 @ M  (8 MFMA) ----
    float invl = __builtin_amdgcn_rcpf(l_run);
    unsigned int ck[4][2];
#pragma unroll
    for (int db = 0; db < 4; ++db)
#pragma unroll
      for (int pr = 0; pr < 2; ++pr)
        ck[db][pr] = pack_bf2(acc_o[db][2 * pr] * invl, acc_o[db][2 * pr + 1] * invl);
    bf16x8 cb[2];
    redist(ck, cb, l4, l15);
    f32x4 o2[4] = {};
#pragma unroll
    for (int db = 0; db < 4; ++db)
#pragma unroll
      for (int h = 0; h < 2; ++h)
        o2[db] = __builtin_amdgcn_mfma_f32_16x16x32_bf16(mf[db][h], cb[h], o2[db], 0, 0, 0);

    // o2: row = d' = 16db+4*l4+r, col = q = l15 -> transpose via padded LDS, store coalesced
    bf16* Os = (bf16*)Ks;   // 64 x 72 pad = 9216 elems, fits easily
#pragma unroll
    for (int db = 0; db < 4; ++db)
#pragma unroll
      for (int r = 0; r < 4; ++r)
        Os[(16 * wave + l15) * 72 + 16 * db + 4 * l4 + r] = __float2bfloat16(o2[db][r]);
    __syncthreads();
    {
      int rr = tid >> 2, cc2 = tid & 3;
      long obase = ((long)(bb * SEQ + Q0 + rr)) * DM + hh * DH + cc2 * 16;
      *(bf16x8*)(ctx2 + obase)     = *(const bf16x8*)(Os + rr * 72 + cc2 * 16);
      *(bf16x8*)(ctx2 + obase + 8) = *(const bf16x8*)(Os + rr * 72 + cc2 * 16 + 8);
    }
  }
#undef STAGE_KV
}

// ---------------- launch ----------------
extern "C" void kernel_launch(void* const* d_in, const int* in_sizes, int n_in,
                              void* d_out, int out_size, void* d_ws, size_t ws_size,
                              hipStream_t stream) {
  (void)in_sizes; (void)n_in; (void)out_size; (void)ws_size;
  const float* X = (const float*)d_in[0];
  const float* W[6]    = {(const float*)d_in[1], (const float*)d_in[3], (const float*)d_in[5],
                          (const float*)d_in[7], (const float*)d_in[9], (const float*)d_in[11]};
  const float* bias[6] = {(const float*)d_in[2], (const float*)d_in[4], (const float*)d_in[6],
                          (const float*)d_in[8], (const float*)d_in[10], (const float*)d_in[12]};

  char* ws = (char*)d_ws;
  bf16* Xb  = (bf16*)(ws);                 // 8 MB (reused as ctx2 after proj GEMM done)
  bf16* Wt  = (bf16*)(ws + (8L  << 20));   // 12 MB (6 x 2MB)
  bf16* qB  = (bf16*)(ws + (20L << 20));   // 8 MB  [BH][S][DH]
  bf16* k1B = (bf16*)(ws + (28L << 20));   // 8 MB  [BH][S][DH]
  bf16* k2t = (bf16*)(ws + (36L << 20));   // 8 MB  [BH][DH][S]
  bf16* v1t = (bf16*)(ws + (44L << 20));   // 8 MB  [BH][DH][S]
  bf16* v2t = (bf16*)(ws + (52L << 20));   // 8 MB  [BH][DH][S]
  float* Mb = (float*)(ws + (60L << 20));  // 512 KB
  bf16* c2  = Xb;                          // reuse: ctx2 [4096][1024]

  WPtrs wp; for (int z = 0; z < 6; ++z) wp.w[z] = W[z];
  prep<<<dim3(32, 32, 8), 256, 0, stream>>>(wp, X, Wt, Xb, Mb);

  ProjArgs pa;
  for (int z = 0; z < 5; ++z) pa.bias[z] = bias[z];
  pa.out[0] = qB; pa.out[1] = k1B; pa.out[2] = k2t; pa.out[3] = v1t; pa.out[4] = v2t;
  gemm_proj<<<1024, 256, 0, stream>>>(Xb, Wt, pa);

  m_kernel<<<dim3(8, 32), 256, 0, stream>>>(k2t, v2t, Mb);

  attn_fused<<<512, 256, 0, stream>>>(qB, k1B, v1t, Mb, c2);

  gemm_out<<<512, 256, 0, stream>>>(c2, Wt + 5L * DM * DM, bias[5], (float*)d_out);
}